// Round 7
// baseline (202.800 us; speedup 1.0000x reference)
//
#include <hip/hip_runtime.h>
#include <math.h>

typedef __attribute__((ext_vector_type(8))) short bf8_t;
typedef __attribute__((ext_vector_type(4))) float f32x4;

#define NB   2
#define N1S  4096
#define N2S  8192
#define CC   64
#define KK   16
#define GQ   8
#define KTILE 2048

// mat ids in wA
#define M_R0 0
#define M_Z0 1
#define M_H0 2
#define M_R1 3
#define M_Z1 4
#define M_H1 5
#define M_FR 6
#define M_FZ 7
#define M_FRO 8

// ---- ws layout (bytes) ----
#define WA_SHORTS   (9*4*2*64*8)                 // 36864 shorts = 73728 B
#define WDIR_OFF    (WA_SHORTS*2)                // 73728
#define WDIR_FLOATS (3*3*64)                     // 576
#define XP_OFF      (WDIR_OFF + WDIR_FLOATS*4)   // 76032 (16B aligned)
#define XP_BYTES    (NB*N2S*16)                  // 262144
#define KIDX_OFF    (XP_OFF + XP_BYTES)          // 338176
#define KIDX_BYTES  (NB*N1S*KK*4)                // 524288
#define P2B_OFF     (KIDX_OFF + KIDX_BYTES)      // 862464 (16B aligned)
#define P2B_BYTES   ((size_t)NB*N2S*CC*2)        // 2 MiB (bf16)

__device__ __forceinline__ float lrelu(float v){ return v > 0.f ? v : 0.1f*v; }
__device__ __forceinline__ float sigm(float v){ return 1.f/(1.f + __expf(-v)); }
__device__ __forceinline__ float tanh_(float v){ return 1.f - 2.f/(__expf(2.f*v) + 1.f); }
__device__ __forceinline__ unsigned short f2bf(float f){
  union { float f; unsigned u; } v; v.f = f;
  unsigned r = v.u + 0x7FFF + ((v.u >> 16) & 1);
  return (unsigned short)(r >> 16);
}

// ---------------- prep: pack 9 weight matrices into A-fragment layout + dir weights ----------------
__global__ __launch_bounds__(256) void prep_wA(
    const float* __restrict__ r0, const float* __restrict__ z0, const float* __restrict__ h0,
    const float* __restrict__ r1, const float* __restrict__ z1, const float* __restrict__ h1,
    const float* __restrict__ fr, const float* __restrict__ fz, const float* __restrict__ fro,
    short* __restrict__ wa, float* __restrict__ wdir)
{
  const float* W[9] = {r0, z0, h0, r1, z1, h1, fr, fz, fro};
  const int Ks[9]   = {67, 67, 67, 64, 64, 64, 64, 64, 64};
  const int stride = gridDim.x * 256;
  for (int i = blockIdx.x*256 + threadIdx.x; i < WA_SHORTS; i += stride) {
    const int j = i & 7, l = (i >> 3) & 63, kk = (i >> 9) & 1, r = (i >> 10) & 3, mat = i >> 12;
    const int row = r*16 + (l & 15);
    const int c = kk*32 + ((l >> 4) << 3) + j;
    wa[i] = (short)f2bf(W[mat][row*Ks[mat] + c]);
  }
  for (int i = blockIdx.x*256 + threadIdx.x; i < WDIR_FLOATS; i += stride) {
    const int g = i / 192, rem = i % 192, d = rem / 64, o = rem & 63;
    wdir[i] = W[g][o*67 + 64 + d];
  }
}

// ---------------- pack xyz2 as float4(x,y,z,|p|^2) ----------------
__global__ __launch_bounds__(256) void pack_xyz2(const float* __restrict__ xyz2, float4* __restrict__ xp){
  const int i = blockIdx.x*256 + threadIdx.x;     // 0 .. 16383
  const int b = i >> 13, j = i & (N2S-1);
  const float x = xyz2[((size_t)(b*3+0))*N2S + j];
  const float y = xyz2[((size_t)(b*3+1))*N2S + j];
  const float z = xyz2[((size_t)(b*3+2))*N2S + j];
  xp[i] = make_float4(x, y, z, (x*x + y*y) + z*z);
}

// ---------------- points2 transpose + bf16: [B,C,N2] f32 -> [B,N2,C] bf16 ----------------
__global__ __launch_bounds__(256) void transpose_p2(const float* __restrict__ src, unsigned short* __restrict__ dst){
  __shared__ float t[64][65];
  const int b = blockIdx.y; const int j0 = blockIdx.x*64;
  const int tx = threadIdx.x & 63; const int r4 = threadIdx.x >> 6;
  #pragma unroll
  for (int c = r4; c < 64; c += 4) t[c][tx] = src[((size_t)b*CC + c)*N2S + j0 + tx];
  __syncthreads();
  #pragma unroll
  for (int j = r4; j < 64; j += 4) dst[((size_t)b*N2S + j0 + j)*CC + tx] = f2bf(t[tx][j]);
}

// ---------------- KNN: 4 queries/wave, two-pass (kappa prune) + exact streaming insert ----------------
__global__ __launch_bounds__(256) void knn_kernel(
    const float* __restrict__ xyz1, const float4* __restrict__ xp, int* __restrict__ idxout)
{
  __shared__ float4 T[KTILE];                      // 32 KB tile
  const int tid = threadIdx.x, w = tid >> 6, lane = tid & 63, grp = lane >> 4;
  const int qbase = blockIdx.x*16 + w*4;           // 16 queries/block; never crosses batch
  const int b = qbase >> 12;
  const float4* __restrict__ X = xp + (b << 13);
  float qx[4], qy[4], qz[4], s1[4], kth[4], kappa[4], m[4];
  #pragma unroll
  for (int g = 0; g < 4; g++) {
    const int n = (qbase + g) & (N1S-1);
    qx[g] = xyz1[((size_t)(b*3+0))*N1S + n];
    qy[g] = xyz1[((size_t)(b*3+1))*N1S + n];
    qz[g] = xyz1[((size_t)(b*3+2))*N1S + n];
    s1[g] = (qx[g]*qx[g] + qy[g]*qy[g]) + qz[g]*qz[g];
    kth[g] = INFINITY; m[g] = INFINITY;
  }

  // ---- pass 1: per-lane minima over private partition, streamed from L2.
  // These values ONLY form the kappa bound; pass 2 + the <16-found guard make the
  // selected set exact w.r.t. pass-2's distance regardless of kappa. ----
  #pragma unroll 2
  for (int c0 = 0; c0 < N2S; c0 += 256) {
    const float4 v0 = X[c0 + lane];
    const float4 v1 = X[c0 + 64 + lane];
    const float4 v2 = X[c0 + 128 + lane];
    const float4 v3 = X[c0 + 192 + lane];
    #pragma unroll
    for (int g = 0; g < 4; g++) {
      const float d0 = (s1[g] + v0.w) - 2.f*((qx[g]*v0.x + qy[g]*v0.y) + qz[g]*v0.z);
      const float d1 = (s1[g] + v1.w) - 2.f*((qx[g]*v1.x + qy[g]*v1.y) + qz[g]*v1.z);
      const float d2 = (s1[g] + v2.w) - 2.f*((qx[g]*v2.x + qy[g]*v2.y) + qz[g]*v2.z);
      const float d3 = (s1[g] + v3.w) - 2.f*((qx[g]*v3.x + qy[g]*v3.y) + qz[g]*v3.z);
      m[g] = fminf(m[g], fminf(fminf(d0, d1), fminf(d2, d3)));
    }
  }
  // kappa[g] = 17th smallest lane-min (> true d16 in pass-2 metric or the guard fires)
  #pragma unroll
  for (int g = 0; g < 4; g++) {
    float v = m[g];
    #pragma unroll
    for (int k = 2; k <= 64; k <<= 1) {
      #pragma unroll
      for (int j = k >> 1; j > 0; j >>= 1) {
        const float pv = __shfl_xor(v, j);
        const bool up = ((lane & k) == 0);
        const bool keepmin = up ? ((lane & j) == 0) : ((lane & j) != 0);
        v = keepmin ? fminf(v, pv) : fmaxf(v, pv);
      }
    }
    kappa[g] = __shfl(v, 16);
  }

  // ---- pass 2: exact streaming insert, ballot gated by min(kth, kappa) ----
  float listd = INFINITY; int listi = 0;
  for (int t0 = 0; t0 < N2S; t0 += KTILE) {
    __syncthreads();
    for (int i = tid; i < KTILE; i += 256) T[i] = X[t0 + i];
    __syncthreads();
    for (int c0 = 0; c0 < KTILE; c0 += 64) {
      const float4 v = T[c0 + lane];
      #pragma unroll
      for (int g = 0; g < 4; g++) {
        // EXACT same distance expression as r3/r4 (keeps neighbor sets identical)
        const float d = (s1[g] + v.w) - 2.f*((qx[g]*v.x + qy[g]*v.y) + qz[g]*v.z);
        unsigned long long vote = __ballot(d < fminf(kth[g], kappa[g]));
        while (vote) {
          const int src = (int)__builtin_ctzll(vote);
          vote &= vote - 1;
          const float dv = __shfl(d, src);
          if (dv < kth[g]) {                       // uniform
            const int iv = t0 + c0 + src;
            const float ud = __shfl_up(listd, 1);
            const int   ui = __shfl_up(listi, 1);
            const bool ing = (grp == g);
            const bool cm = ing && (dv < listd);   // strict < keeps lower index on ties
            const bool cp = cm && ((lane & 15) > 0) && (dv < ud);
            listd = cm ? (cp ? ud : dv) : listd;
            listi = cm ? (cp ? ui : iv) : listi;
            kth[g] = __shfl(listd, g*16 + 15);
          }
        }
      }
    }
  }

  // ---- exactness guard: if <16 found (kth stayed INF), rescan that query unpruned ----
  {
    bool need = false;
    #pragma unroll
    for (int g = 0; g < 4; g++) need = need || (kth[g] == INFINITY);
    if (__builtin_expect(need, 0)) {
      #pragma unroll
      for (int g = 0; g < 4; g++) {
        if (kth[g] == INFINITY) {                  // uniform
          if (grp == g) { listd = INFINITY; listi = 0; }
          float kk2 = INFINITY;
          for (int c0 = 0; c0 < N2S; c0 += 64) {
            const float4 v = X[c0 + lane];
            const float d = (s1[g] + v.w) - 2.f*((qx[g]*v.x + qy[g]*v.y) + qz[g]*v.z);
            unsigned long long vote = __ballot(d < kk2);
            while (vote) {
              const int src = (int)__builtin_ctzll(vote);
              vote &= vote - 1;
              const float dv = __shfl(d, src);
              if (dv < kk2) {
                const int iv = c0 + src;
                const float ud = __shfl_up(listd, 1);
                const int   ui = __shfl_up(listi, 1);
                const bool ing = (grp == g);
                const bool cm = ing && (dv < listd);
                const bool cp = cm && ((lane & 15) > 0) && (dv < ud);
                listd = cm ? (cp ? ud : dv) : listd;
                listi = cm ? (cp ? ui : iv) : listi;
                kk2 = __shfl(listd, g*16 + 15);
              }
            }
          }
        }
      }
    }
  }
  idxout[(size_t)(qbase + grp)*KK + (lane & 15)] = listi;
}

// ---------------- gates: MFMA pipeline, 8 queries / block, 4 waves = 4 row-tiles ----------------
#define FRAG(mat, kk) (*(const bf8_t*)(wA + (((mat)*4 + w)*2 + (kk))*512 + lane*8))

__global__ __launch_bounds__(256) void gates_kernel(
    const float* __restrict__ xyz1, const float* __restrict__ xyz2,
    const float* __restrict__ points1, const unsigned short* __restrict__ p2b,
    const int* __restrict__ kidx, const short* __restrict__ wA,
    const float* __restrict__ wdir,
    const float* __restrict__ b_r0, const float* __restrict__ b_z0,
    const float* __restrict__ b_h0, const float* __restrict__ b_r1,
    const float* __restrict__ b_z1, const float* __restrict__ b_h1,
    float* __restrict__ out)
{
  __shared__ __align__(16) short featB[2][GQ][64][8];  // p2 channels, B-frag packed (16 KB)
  __shared__ __align__(16) short rB[2][GQ][64][8];     // r0 acts, then r*p1 in-place (16 KB)
  __shared__ __align__(16) float p1f[64][GQ];
  __shared__ __align__(16) short p1B[2][64][8];
  __shared__ float BFr[64][GQ], BFz[64][GQ];
  __shared__ float zmaxL[64][GQ], hmaxL[64][GQ];
  __shared__ float biasL[6][64];
  __shared__ float dirL[3][GQ*KK];
  __shared__ __align__(16) float obuf[64][GQ];

  const int tid = threadIdx.x;
  const int w = tid >> 6, lane = tid & 63;
  const int b  = blockIdx.x >> 9;
  const int n0 = (blockIdx.x & 511) * GQ;
  const int cq = lane & 15;                       // C col within tile (= query q)
  const int reg_o0 = w*16 + ((lane >> 4) << 2);   // first of this lane's 4 C rows
  const f32x4 zero4 = {0.f, 0.f, 0.f, 0.f};

  // ---- P0a ----
  for (int i = tid; i < 6*64; i += 256) {
    const int a = i >> 6, o = i & 63;
    const float* bp = (a==0)?b_r0:(a==1)?b_z0:(a==2)?b_h0:(a==3)?b_r1:(a==4)?b_z1:b_h1;
    biasL[a][o] = bp[o];
  }
  if (tid < 64) {
    const float* sp = points1 + ((size_t)(b*CC + tid))*N1S + n0;
    *(float4*)&p1f[tid][0] = ((const float4*)sp)[0];
    *(float4*)&p1f[tid][4] = ((const float4*)sp)[1];
  }
  ((unsigned long long*)&p1B[0][0][0])[tid] = 0ULL;   // zero 2048 B
  if (tid < 128) {                                    // dir channels
    const int m = tid, qg = n0 + (m >> 4);
    const int j = kidx[(size_t)((b << 12) + qg)*KK + (m & 15)];
    #pragma unroll
    for (int d = 0; d < 3; d++)
      dirL[d][m] = xyz2[((size_t)(b*3+d))*N2S + j] - xyz1[((size_t)(b*3+d))*N1S + qg];
  }
  {                                                   // p2 feature gather (bf16) -> featB (B-frag packed)
    const int m = tid >> 1, half = tid & 1;
    const int ct = m >> 4;
    const int qg = n0 + ct;
    const int j = kidx[(size_t)((b << 12) + qg)*KK + (m & 15)];
    const uint4* __restrict__ src = (const uint4*)(p2b + (((size_t)(b << 13) + j)*CC + half*32));
    #pragma unroll
    for (int gi = 0; gi < 4; gi++)
      *(uint4*)&featB[half][ct][gi*16 + (m & 15)][0] = src[gi];
  }
  __syncthreads();

  // ---- P0b: p1 as B-frag (cols 0..7 valid, rest zero) ----
  {
    const int s0 = tid*4;
    const int j0 = s0 & 7, l = (s0 >> 3) & 63, kk = s0 >> 9;
    const int q = l & 15;
    if (q < 8) {
      unsigned short t0[4];
      #pragma unroll
      for (int jj = 0; jj < 4; jj++)
        t0[jj] = f2bf(p1f[kk*32 + ((l >> 4) << 3) + j0 + jj][q]);
      uint2 pk; pk.x = t0[0] | ((unsigned)t0[1] << 16); pk.y = t0[2] | ((unsigned)t0[3] << 16);
      *(uint2*)&p1B[kk][l][j0] = pk;
    }
  }
  __syncthreads();

  // ---- P1: fuse GEMMs -> BFr/BFz ----
  {
    const bf8_t fa0 = FRAG(M_FR, 0), fa1 = FRAG(M_FR, 1);
    const bf8_t ga0 = FRAG(M_FZ, 0), ga1 = FRAG(M_FZ, 1);
    const bf8_t pb0 = *(const bf8_t*)&p1B[0][lane][0];
    const bf8_t pb1 = *(const bf8_t*)&p1B[1][lane][0];
    f32x4 ar = __builtin_amdgcn_mfma_f32_16x16x32_bf16(fa0, pb0, zero4, 0, 0, 0);
    ar = __builtin_amdgcn_mfma_f32_16x16x32_bf16(fa1, pb1, ar, 0, 0, 0);
    f32x4 az = __builtin_amdgcn_mfma_f32_16x16x32_bf16(ga0, pb0, zero4, 0, 0, 0);
    az = __builtin_amdgcn_mfma_f32_16x16x32_bf16(ga1, pb1, az, 0, 0, 0);
    if (cq < 8) {
      #pragma unroll
      for (int r2 = 0; r2 < 4; r2++) {
        const int o = reg_o0 + r2;
        BFr[o][cq] = ar[r2] + biasL[0][o];
        BFz[o][cq] = az[r2] + biasL[1][o];
      }
    }
  }

  // ---- P1b: layer-0 r/z (+dir epilogue), write r0 B-frags, z max-reduce ----
  {
    const bf8_t ra0 = FRAG(M_R0, 0), ra1 = FRAG(M_R0, 1);
    const bf8_t za0 = FRAG(M_Z0, 0), za1 = FRAG(M_Z0, 1);
    float wdr[3][4], wdz[3][4];
    #pragma unroll
    for (int d = 0; d < 3; d++)
      #pragma unroll
      for (int r2 = 0; r2 < 4; r2++) {
        wdr[d][r2] = wdir[(0*3 + d)*64 + reg_o0 + r2];
        wdz[d][r2] = wdir[(1*3 + d)*64 + reg_o0 + r2];
      }
    const int kkv = reg_o0 >> 5, lp = ((reg_o0 & 31) >> 3)*16 + cq, j0 = reg_o0 & 7;
    #pragma unroll
    for (int ct = 0; ct < GQ; ct++) {
      const bf8_t fb0 = *(const bf8_t*)&featB[0][ct][lane][0];
      const bf8_t fb1 = *(const bf8_t*)&featB[1][ct][lane][0];
      f32x4 accr = __builtin_amdgcn_mfma_f32_16x16x32_bf16(ra0, fb0, zero4, 0, 0, 0);
      accr = __builtin_amdgcn_mfma_f32_16x16x32_bf16(ra1, fb1, accr, 0, 0, 0);
      f32x4 accz = __builtin_amdgcn_mfma_f32_16x16x32_bf16(za0, fb0, zero4, 0, 0, 0);
      accz = __builtin_amdgcn_mfma_f32_16x16x32_bf16(za1, fb1, accz, 0, 0, 0);
      const int m = ct*16 + cq;
      const float d0 = dirL[0][m], d1 = dirL[1][m], d2 = dirL[2][m];
      unsigned short rpk[4]; float zv[4];
      #pragma unroll
      for (int r2 = 0; r2 < 4; r2++) {
        const int o = reg_o0 + r2;
        float rv = accr[r2] + BFr[o][ct] + wdr[0][r2]*d0 + wdr[1][r2]*d1 + wdr[2][r2]*d2;
        rpk[r2] = f2bf(lrelu(rv));
        float zt = accz[r2] + BFz[o][ct] + wdz[0][r2]*d0 + wdz[1][r2]*d1 + wdz[2][r2]*d2;
        zv[r2] = lrelu(zt);
      }
      uint2 pk; pk.x = rpk[0] | ((unsigned)rpk[1] << 16); pk.y = rpk[2] | ((unsigned)rpk[3] << 16);
      *(uint2*)&rB[kkv][ct][lp][j0] = pk;
      #pragma unroll
      for (int r2 = 0; r2 < 4; r2++) {
        float vv = zv[r2];
        vv = fmaxf(vv, __shfl_xor(vv, 1));
        vv = fmaxf(vv, __shfl_xor(vv, 2));
        vv = fmaxf(vv, __shfl_xor(vv, 4));
        vv = fmaxf(vv, __shfl_xor(vv, 8));
        zv[r2] = vv;
      }
      if (cq == 0) {
        #pragma unroll
        for (int r2 = 0; r2 < 4; r2++) zmaxL[reg_o0 + r2][ct] = zv[r2];
      }
    }
  }
  __syncthreads();

  // ---- P2: r1 (hold r*p1 packed in regs), z1 ----
  uint2 rpK[GQ];
  float zg[4];
  {
    const bf8_t r1a0 = FRAG(M_R1, 0), r1a1 = FRAG(M_R1, 1);
    #pragma unroll
    for (int ct = 0; ct < GQ; ct++) {
      const bf8_t b0 = *(const bf8_t*)&rB[0][ct][lane][0];
      const bf8_t b1 = *(const bf8_t*)&rB[1][ct][lane][0];
      f32x4 acc = __builtin_amdgcn_mfma_f32_16x16x32_bf16(r1a0, b0, zero4, 0, 0, 0);
      acc = __builtin_amdgcn_mfma_f32_16x16x32_bf16(r1a1, b1, acc, 0, 0, 0);
      unsigned short pk4[4];
      #pragma unroll
      for (int r2 = 0; r2 < 4; r2++) {
        const int o = reg_o0 + r2;
        const float rg = sigm(acc[r2] + biasL[3][o]);
        pk4[r2] = f2bf(rg * p1f[o][ct]);
      }
      rpK[ct].x = pk4[0] | ((unsigned)pk4[1] << 16);
      rpK[ct].y = pk4[2] | ((unsigned)pk4[3] << 16);
    }
    const bf8_t z1a0 = FRAG(M_Z1, 0), z1a1 = FRAG(M_Z1, 1);
    const int qc = cq < 8 ? cq : 7;
    bf8_t zb0, zb1;
    #pragma unroll
    for (int j = 0; j < 8; j++) {
      zb0[j] = (short)f2bf(zmaxL[((lane >> 4) << 3) + j][qc]);
      zb1[j] = (short)f2bf(zmaxL[32 + ((lane >> 4) << 3) + j][qc]);
    }
    f32x4 az = __builtin_amdgcn_mfma_f32_16x16x32_bf16(z1a0, zb0, zero4, 0, 0, 0);
    az = __builtin_amdgcn_mfma_f32_16x16x32_bf16(z1a1, zb1, az, 0, 0, 0);
    #pragma unroll
    for (int r2 = 0; r2 < 4; r2++) zg[r2] = sigm(az[r2] + biasL[4][reg_o0 + r2]);
  }
  __syncthreads();

  // ---- P2b: overwrite rB with r*p1 ----
  {
    const int kkv = reg_o0 >> 5, lp = ((reg_o0 & 31) >> 3)*16 + cq, j0 = reg_o0 & 7;
    #pragma unroll
    for (int ct = 0; ct < GQ; ct++) *(uint2*)&rB[kkv][ct][lp][j0] = rpK[ct];
  }
  __syncthreads();

  // ---- P3: h0·feat + fro·(r*p1) (+dir), h max-reduce ----
  {
    const bf8_t h0a0 = FRAG(M_H0, 0), h0a1 = FRAG(M_H0, 1);
    const bf8_t foa0 = FRAG(M_FRO, 0), foa1 = FRAG(M_FRO, 1);
    float wdh[3][4];
    #pragma unroll
    for (int d = 0; d < 3; d++)
      #pragma unroll
      for (int r2 = 0; r2 < 4; r2++) wdh[d][r2] = wdir[(2*3 + d)*64 + reg_o0 + r2];
    #pragma unroll
    for (int ct = 0; ct < GQ; ct++) {
      const bf8_t fb0 = *(const bf8_t*)&featB[0][ct][lane][0];
      const bf8_t fb1 = *(const bf8_t*)&featB[1][ct][lane][0];
      const bf8_t rb0 = *(const bf8_t*)&rB[0][ct][lane][0];
      const bf8_t rb1 = *(const bf8_t*)&rB[1][ct][lane][0];
      f32x4 acc = __builtin_amdgcn_mfma_f32_16x16x32_bf16(h0a0, fb0, zero4, 0, 0, 0);
      acc = __builtin_amdgcn_mfma_f32_16x16x32_bf16(h0a1, fb1, acc, 0, 0, 0);
      acc = __builtin_amdgcn_mfma_f32_16x16x32_bf16(foa0, rb0, acc, 0, 0, 0);
      acc = __builtin_amdgcn_mfma_f32_16x16x32_bf16(foa1, rb1, acc, 0, 0, 0);
      const int m = ct*16 + cq;
      const float d0 = dirL[0][m], d1 = dirL[1][m], d2 = dirL[2][m];
      float hv[4];
      #pragma unroll
      for (int r2 = 0; r2 < 4; r2++) {
        const int o = reg_o0 + r2;
        hv[r2] = lrelu(acc[r2] + biasL[2][o] + wdh[0][r2]*d0 + wdh[1][r2]*d1 + wdh[2][r2]*d2);
      }
      #pragma unroll
      for (int r2 = 0; r2 < 4; r2++) {
        float vv = hv[r2];
        vv = fmaxf(vv, __shfl_xor(vv, 1));
        vv = fmaxf(vv, __shfl_xor(vv, 2));
        vv = fmaxf(vv, __shfl_xor(vv, 4));
        vv = fmaxf(vv, __shfl_xor(vv, 8));
        hv[r2] = vv;
      }
      if (cq == 0) {
        #pragma unroll
        for (int r2 = 0; r2 < 4; r2++) hmaxL[reg_o0 + r2][ct] = hv[r2];
      }
    }
  }
  __syncthreads();

  // ---- P4: h1, final blend ----
  {
    const bf8_t h1a0 = FRAG(M_H1, 0), h1a1 = FRAG(M_H1, 1);
    const int qc = cq < 8 ? cq : 7;
    bf8_t hb0, hb1;
    #pragma unroll
    for (int j = 0; j < 8; j++) {
      hb0[j] = (short)f2bf(hmaxL[((lane >> 4) << 3) + j][qc]);
      hb1[j] = (short)f2bf(hmaxL[32 + ((lane >> 4) << 3) + j][qc]);
    }
    f32x4 ah = __builtin_amdgcn_mfma_f32_16x16x32_bf16(h1a0, hb0, zero4, 0, 0, 0);
    ah = __builtin_amdgcn_mfma_f32_16x16x32_bf16(h1a1, hb1, ah, 0, 0, 0);
    if (cq < 8) {
      #pragma unroll
      for (int r2 = 0; r2 < 4; r2++) {
        const int o = reg_o0 + r2;
        const float hg = tanh_(ah[r2] + biasL[5][o]);
        obuf[o][cq] = (1.f - zg[r2])*p1f[o][cq] + zg[r2]*hg;
      }
    }
  }
  __syncthreads();
  if (tid < 128) {
    const int c = tid >> 1, q4 = (tid & 1)*4;
    *(float4*)(out + ((size_t)(b*CC + c))*N1S + n0 + q4) = *(float4*)&obuf[c][q4];
  }
}

extern "C" void kernel_launch(void* const* d_in, const int* in_sizes, int n_in,
                              void* d_out, int out_size, void* d_ws, size_t ws_size,
                              hipStream_t stream) {
  const float* xyz1    = (const float*)d_in[0];
  const float* xyz2    = (const float*)d_in[1];
  const float* points1 = (const float*)d_in[2];
  const float* points2 = (const float*)d_in[3];
  const float* w_r0 = (const float*)d_in[4];
  const float* b_r0 = (const float*)d_in[5];
  const float* w_r1 = (const float*)d_in[6];
  const float* b_r1 = (const float*)d_in[7];
  const float* w_z0 = (const float*)d_in[8];
  const float* b_z0 = (const float*)d_in[9];
  const float* w_z1 = (const float*)d_in[10];
  const float* b_z1 = (const float*)d_in[11];
  const float* w_h0 = (const float*)d_in[12];
  const float* b_h0 = (const float*)d_in[13];
  const float* w_h1 = (const float*)d_in[14];
  const float* b_h1 = (const float*)d_in[15];
  const float* w_fr  = (const float*)d_in[16];
  const float* w_fz  = (const float*)d_in[17];
  const float* w_fro = (const float*)d_in[18];
  float* out = (float*)d_out;

  short*  wa   = (short*)d_ws;
  float*  wdir = (float*)((char*)d_ws + WDIR_OFF);
  float4* xp   = (float4*)((char*)d_ws + XP_OFF);
  int*    kidx = (int*)((char*)d_ws + KIDX_OFF);
  unsigned short* p2b = (unsigned short*)((char*)d_ws + P2B_OFF);

  prep_wA<<<16, 256, 0, stream>>>(w_r0, w_z0, w_h0, w_r1, w_z1, w_h1,
                                  w_fr, w_fz, w_fro, wa, wdir);
  pack_xyz2<<<64, 256, 0, stream>>>(xyz2, xp);
  transpose_p2<<<dim3(N2S/64, NB), dim3(256), 0, stream>>>(points2, p2b);

  knn_kernel<<<512, 256, 0, stream>>>(xyz1, xp, kidx);

  gates_kernel<<<1024, 256, 0, stream>>>(
      xyz1, xyz2, points1, p2b, kidx, wa, wdir,
      b_r0, b_z0, b_h0, b_r1, b_z1, b_h1, out);
}

// Round 9
// 199.167 us; speedup vs baseline: 1.0182x; 1.0182x over previous
//
#include <hip/hip_runtime.h>
#include <math.h>

typedef __attribute__((ext_vector_type(8))) short bf8_t;
typedef __attribute__((ext_vector_type(4))) float f32x4;

#define NB   2
#define N1S  4096
#define N2S  8192
#define CC   64
#define KK   16
#define GQ   8

// mat ids in wA
#define M_R0 0
#define M_Z0 1
#define M_H0 2
#define M_R1 3
#define M_Z1 4
#define M_H1 5
#define M_FR 6
#define M_FZ 7
#define M_FRO 8

// ---- ws layout (bytes) ----
#define WA_SHORTS   (9*4*2*64*8)                 // 36864 shorts = 73728 B
#define WDIR_OFF    (WA_SHORTS*2)                // 73728
#define WDIR_FLOATS (3*3*64)                     // 576
#define XP_OFF      (WDIR_OFF + WDIR_FLOATS*4)   // 76032 (16B aligned)
#define XP_BYTES    (NB*N2S*16)                  // 262144
#define KIDX_OFF    (XP_OFF + XP_BYTES)          // 338176
#define KIDX_BYTES  (NB*N1S*KK*4)                // 524288
#define P2B_OFF     (KIDX_OFF + KIDX_BYTES)      // 862464 (16B aligned)
#define P2B_BYTES   ((size_t)NB*N2S*CC*2)        // 2 MiB (bf16)

__device__ __forceinline__ float lrelu(float v){ return v > 0.f ? v : 0.1f*v; }
__device__ __forceinline__ float sigm(float v){ return 1.f/(1.f + __expf(-v)); }
__device__ __forceinline__ float tanh_(float v){ return 1.f - 2.f/(__expf(2.f*v) + 1.f); }
__device__ __forceinline__ unsigned short f2bf(float f){
  union { float f; unsigned u; } v; v.f = f;
  unsigned r = v.u + 0x7FFF + ((v.u >> 16) & 1);
  return (unsigned short)(r >> 16);
}

// ---------------- prep: pack 9 weight matrices into A-fragment layout + dir weights ----------------
__global__ __launch_bounds__(256) void prep_wA(
    const float* __restrict__ r0, const float* __restrict__ z0, const float* __restrict__ h0,
    const float* __restrict__ r1, const float* __restrict__ z1, const float* __restrict__ h1,
    const float* __restrict__ fr, const float* __restrict__ fz, const float* __restrict__ fro,
    short* __restrict__ wa, float* __restrict__ wdir)
{
  const float* W[9] = {r0, z0, h0, r1, z1, h1, fr, fz, fro};
  const int Ks[9]   = {67, 67, 67, 64, 64, 64, 64, 64, 64};
  const int stride = gridDim.x * 256;
  for (int i = blockIdx.x*256 + threadIdx.x; i < WA_SHORTS; i += stride) {
    const int j = i & 7, l = (i >> 3) & 63, kk = (i >> 9) & 1, r = (i >> 10) & 3, mat = i >> 12;
    const int row = r*16 + (l & 15);
    const int c = kk*32 + ((l >> 4) << 3) + j;
    wa[i] = (short)f2bf(W[mat][row*Ks[mat] + c]);
  }
  for (int i = blockIdx.x*256 + threadIdx.x; i < WDIR_FLOATS; i += stride) {
    const int g = i / 192, rem = i % 192, d = rem / 64, o = rem & 63;
    wdir[i] = W[g][o*67 + 64 + d];
  }
}

// ---------------- pack xyz2 as float4(x,y,z,|p|^2) ----------------
__global__ __launch_bounds__(256) void pack_xyz2(const float* __restrict__ xyz2, float4* __restrict__ xp){
  const int i = blockIdx.x*256 + threadIdx.x;     // 0 .. 16383
  const int b = i >> 13, j = i & (N2S-1);
  const float x = xyz2[((size_t)(b*3+0))*N2S + j];
  const float y = xyz2[((size_t)(b*3+1))*N2S + j];
  const float z = xyz2[((size_t)(b*3+2))*N2S + j];
  xp[i] = make_float4(x, y, z, (x*x + y*y) + z*z);
}

// ---------------- points2 transpose + bf16: [B,C,N2] f32 -> [B,N2,C] bf16 ----------------
__global__ __launch_bounds__(256) void transpose_p2(const float* __restrict__ src, unsigned short* __restrict__ dst){
  __shared__ float t[64][65];
  const int b = blockIdx.y; const int j0 = blockIdx.x*64;
  const int tx = threadIdx.x & 63; const int r4 = threadIdx.x >> 6;
  #pragma unroll
  for (int c = r4; c < 64; c += 4) t[c][tx] = src[((size_t)b*CC + c)*N2S + j0 + tx];
  __syncthreads();
  #pragma unroll
  for (int j = r4; j < 64; j += 4) dst[((size_t)b*N2S + j0 + j)*CC + tx] = f2bf(t[tx][j]);
}

// ---------------- KNN: candidate-split. Block = 4 queries, 4 waves.
// Wave w: queries (w>>1)*2 + {0,1}, candidate half = w&1 (4096 candidates).
// Per-half two-pass (kappa prune + exact gated insert + guard), then in-LDS
// 64-lane bitonic merge of the two per-half top-16 lists keyed (d, idx). ----------------
__global__ __launch_bounds__(256) void knn_kernel(
    const float* __restrict__ xyz1, const float4* __restrict__ xp, int* __restrict__ idxout)
{
  __shared__ float pdL[4][2][16];
  __shared__ int   piL[4][2][16];
  const int tid = threadIdx.x, w = tid >> 6, lane = tid & 63, grp = lane >> 4;
  const int qbase = blockIdx.x*4;                  // 4 queries/block; never crosses batch
  const int b = qbase >> 12;
  const int q0 = qbase + (w >> 1)*2;               // this wave's first query
  const int half = w & 1;
  const int hbase = half*(N2S/2);
  const float4* __restrict__ X = xp + (b << 13);
  float qx[2], qy[2], qz[2], s1[2], kth[2], kappa[2], m[2];
  #pragma unroll
  for (int g = 0; g < 2; g++) {
    const int n = (q0 + g) & (N1S-1);
    qx[g] = xyz1[((size_t)(b*3+0))*N1S + n];
    qy[g] = xyz1[((size_t)(b*3+1))*N1S + n];
    qz[g] = xyz1[((size_t)(b*3+2))*N1S + n];
    s1[g] = (qx[g]*qx[g] + qy[g]*qy[g]) + qz[g]*qz[g];
    kth[g] = INFINITY; m[g] = INFINITY;
  }

  // ---- pass 1: per-lane minima over this half's private partitions (L2-streamed).
  // Values ONLY form the kappa bound; pass 2 + guard make the set exact regardless. ----
  #pragma unroll 2
  for (int c0 = 0; c0 < N2S/2; c0 += 256) {
    const float4 v0 = X[hbase + c0 + lane];
    const float4 v1 = X[hbase + c0 + 64 + lane];
    const float4 v2 = X[hbase + c0 + 128 + lane];
    const float4 v3 = X[hbase + c0 + 192 + lane];
    #pragma unroll
    for (int g = 0; g < 2; g++) {
      const float d0 = (s1[g] + v0.w) - 2.f*((qx[g]*v0.x + qy[g]*v0.y) + qz[g]*v0.z);
      const float d1 = (s1[g] + v1.w) - 2.f*((qx[g]*v1.x + qy[g]*v1.y) + qz[g]*v1.z);
      const float d2 = (s1[g] + v2.w) - 2.f*((qx[g]*v2.x + qy[g]*v2.y) + qz[g]*v2.z);
      const float d3 = (s1[g] + v3.w) - 2.f*((qx[g]*v3.x + qy[g]*v3.y) + qz[g]*v3.z);
      m[g] = fminf(m[g], fminf(fminf(d0, d1), fminf(d2, d3)));
    }
  }
  // kappa[g] = 17th smallest lane-min (> this half's true d16, or the guard fires)
  #pragma unroll
  for (int g = 0; g < 2; g++) {
    float v = m[g];
    #pragma unroll
    for (int k = 2; k <= 64; k <<= 1) {
      #pragma unroll
      for (int j = k >> 1; j > 0; j >>= 1) {
        const float pv = __shfl_xor(v, j);
        const bool up = ((lane & k) == 0);
        const bool keepmin = up ? ((lane & j) == 0) : ((lane & j) != 0);
        v = keepmin ? fminf(v, pv) : fmaxf(v, pv);
      }
    }
    kappa[g] = __shfl(v, 16);
  }

  // ---- pass 2: exact streaming insert over this half, gated by min(kth, kappa) ----
  float listd = INFINITY; int listi = 0;
  #pragma unroll 2
  for (int c0 = 0; c0 < N2S/2; c0 += 64) {
    const float4 v = X[hbase + c0 + lane];
    #pragma unroll
    for (int g = 0; g < 2; g++) {
      // EXACT same distance expression as r3..r7 (keeps neighbor sets identical)
      const float d = (s1[g] + v.w) - 2.f*((qx[g]*v.x + qy[g]*v.y) + qz[g]*v.z);
      unsigned long long vote = __ballot(d < fminf(kth[g], kappa[g]));
      while (vote) {
        const int src = (int)__builtin_ctzll(vote);
        vote &= vote - 1;
        const float dv = __shfl(d, src);
        if (dv < kth[g]) {                       // uniform
          const int iv = hbase + c0 + src;
          const float ud = __shfl_up(listd, 1);
          const int   ui = __shfl_up(listi, 1);
          const bool ing = (grp == g);
          const bool cm = ing && (dv < listd);   // strict < keeps lower index on ties
          const bool cp = cm && ((lane & 15) > 0) && (dv < ud);
          listd = cm ? (cp ? ud : dv) : listd;
          listi = cm ? (cp ? ui : iv) : listi;
          kth[g] = __shfl(listd, g*16 + 15);
        }
      }
    }
  }

  // ---- exactness guard: if <16 found in this half, rescan the half unpruned ----
  {
    bool need = false;
    #pragma unroll
    for (int g = 0; g < 2; g++) need = need || (kth[g] == INFINITY);
    if (__builtin_expect(need, 0)) {
      #pragma unroll
      for (int g = 0; g < 2; g++) {
        if (kth[g] == INFINITY) {                // uniform
          if (grp == g) { listd = INFINITY; listi = 0; }
          float kk2 = INFINITY;
          for (int c0 = 0; c0 < N2S/2; c0 += 64) {
            const float4 v = X[hbase + c0 + lane];
            const float d = (s1[g] + v.w) - 2.f*((qx[g]*v.x + qy[g]*v.y) + qz[g]*v.z);
            unsigned long long vote = __ballot(d < kk2);
            while (vote) {
              const int src = (int)__builtin_ctzll(vote);
              vote &= vote - 1;
              const float dv = __shfl(d, src);
              if (dv < kk2) {
                const int iv = hbase + c0 + src;
                const float ud = __shfl_up(listd, 1);
                const int   ui = __shfl_up(listi, 1);
                const bool ing = (grp == g);
                const bool cm = ing && (dv < listd);
                const bool cp = cm && ((lane & 15) > 0) && (dv < ud);
                listd = cm ? (cp ? ud : dv) : listd;
                listi = cm ? (cp ? ui : iv) : listi;
                kk2 = __shfl(listd, g*16 + 15);
              }
            }
          }
        }
      }
    }
  }

  // ---- store per-half partial lists ----
  if (grp < 2) {
    const int qi = (w >> 1)*2 + grp;
    pdL[qi][half][lane & 15] = listd;
    piL[qi][half][lane & 15] = listi;
  }
  __syncthreads();

  // ---- merge: wave w merges query qbase+w via 64-lane bitonic sort on (d, idx) ----
  {
    float d = (lane < 32) ? pdL[w][lane >> 4][lane & 15] : INFINITY;
    int   i = (lane < 32) ? piL[w][lane >> 4][lane & 15] : 0x7fffffff;
    #pragma unroll
    for (int k = 2; k <= 64; k <<= 1) {
      #pragma unroll
      for (int j = k >> 1; j > 0; j >>= 1) {
        const float pdv = __shfl_xor(d, j);
        const int   piv = __shfl_xor(i, j);
        const bool keepmin = (((lane & k) == 0) == ((lane & j) == 0));
        const bool ownless = (d < pdv) || (d == pdv && i < piv);
        const bool takeown = keepmin ? ownless : !ownless;
        d = takeown ? d : pdv;
        i = takeown ? i : piv;
      }
    }
    if (lane < KK) idxout[(size_t)(qbase + w)*KK + lane] = i;
  }
}

// ---------------- gates: MFMA pipeline, 8 queries / block, 4 waves = 4 row-tiles ----------------
#define FRAG(mat, kk) (*(const bf8_t*)(wA + (((mat)*4 + w)*2 + (kk))*512 + lane*8))

__global__ __launch_bounds__(256) void gates_kernel(
    const float* __restrict__ xyz1, const float* __restrict__ xyz2,
    const float* __restrict__ points1, const unsigned short* __restrict__ p2b,
    const int* __restrict__ kidx, const short* __restrict__ wA,
    const float* __restrict__ wdir,
    const float* __restrict__ b_r0, const float* __restrict__ b_z0,
    const float* __restrict__ b_h0, const float* __restrict__ b_r1,
    const float* __restrict__ b_z1, const float* __restrict__ b_h1,
    float* __restrict__ out)
{
  __shared__ __align__(16) short featB[2][GQ][64][8];  // p2 channels, B-frag packed (16 KB)
  __shared__ __align__(16) short rB[2][GQ][64][8];     // r0 acts, then r*p1 in-place (16 KB)
  __shared__ __align__(16) float p1f[64][GQ];
  __shared__ __align__(16) short p1B[2][64][8];
  __shared__ float BFr[64][GQ], BFz[64][GQ];
  __shared__ float zmaxL[64][GQ], hmaxL[64][GQ];
  __shared__ float biasL[6][64];
  __shared__ float dirL[3][GQ*KK];
  __shared__ __align__(16) float obuf[64][GQ];

  const int tid = threadIdx.x;
  const int w = tid >> 6, lane = tid & 63;
  const int b  = blockIdx.x >> 9;
  const int n0 = (blockIdx.x & 511) * GQ;
  const int cq = lane & 15;                       // C col within tile (= query q)
  const int reg_o0 = w*16 + ((lane >> 4) << 2);   // first of this lane's 4 C rows
  const f32x4 zero4 = {0.f, 0.f, 0.f, 0.f};

  // ---- P0a ----
  for (int i = tid; i < 6*64; i += 256) {
    const int a = i >> 6, o = i & 63;
    const float* bp = (a==0)?b_r0:(a==1)?b_z0:(a==2)?b_h0:(a==3)?b_r1:(a==4)?b_z1:b_h1;
    biasL[a][o] = bp[o];
  }
  if (tid < 64) {
    const float* sp = points1 + ((size_t)(b*CC + tid))*N1S + n0;
    *(float4*)&p1f[tid][0] = ((const float4*)sp)[0];
    *(float4*)&p1f[tid][4] = ((const float4*)sp)[1];
  }
  ((unsigned long long*)&p1B[0][0][0])[tid] = 0ULL;   // zero 2048 B
  if (tid < 128) {                                    // dir channels
    const int m = tid, qg = n0 + (m >> 4);
    const int j = kidx[(size_t)((b << 12) + qg)*KK + (m & 15)];
    #pragma unroll
    for (int d = 0; d < 3; d++)
      dirL[d][m] = xyz2[((size_t)(b*3+d))*N2S + j] - xyz1[((size_t)(b*3+d))*N1S + qg];
  }
  {                                                   // p2 feature gather (bf16) -> featB (B-frag packed)
    const int m = tid >> 1, half = tid & 1;
    const int ct = m >> 4;
    const int qg = n0 + ct;
    const int j = kidx[(size_t)((b << 12) + qg)*KK + (m & 15)];
    const uint4* __restrict__ src = (const uint4*)(p2b + (((size_t)(b << 13) + j)*CC + half*32));
    #pragma unroll
    for (int gi = 0; gi < 4; gi++)
      *(uint4*)&featB[half][ct][gi*16 + (m & 15)][0] = src[gi];
  }
  __syncthreads();

  // ---- P0b: p1 as B-frag (cols 0..7 valid, rest zero) ----
  {
    const int s0 = tid*4;
    const int j0 = s0 & 7, l = (s0 >> 3) & 63, kk = s0 >> 9;
    const int q = l & 15;
    if (q < 8) {
      unsigned short t0[4];
      #pragma unroll
      for (int jj = 0; jj < 4; jj++)
        t0[jj] = f2bf(p1f[kk*32 + ((l >> 4) << 3) + j0 + jj][q]);
      uint2 pk; pk.x = t0[0] | ((unsigned)t0[1] << 16); pk.y = t0[2] | ((unsigned)t0[3] << 16);
      *(uint2*)&p1B[kk][l][j0] = pk;
    }
  }
  __syncthreads();

  // ---- P1: fuse GEMMs -> BFr/BFz ----
  {
    const bf8_t fa0 = FRAG(M_FR, 0), fa1 = FRAG(M_FR, 1);
    const bf8_t ga0 = FRAG(M_FZ, 0), ga1 = FRAG(M_FZ, 1);
    const bf8_t pb0 = *(const bf8_t*)&p1B[0][lane][0];
    const bf8_t pb1 = *(const bf8_t*)&p1B[1][lane][0];
    f32x4 ar = __builtin_amdgcn_mfma_f32_16x16x32_bf16(fa0, pb0, zero4, 0, 0, 0);
    ar = __builtin_amdgcn_mfma_f32_16x16x32_bf16(fa1, pb1, ar, 0, 0, 0);
    f32x4 az = __builtin_amdgcn_mfma_f32_16x16x32_bf16(ga0, pb0, zero4, 0, 0, 0);
    az = __builtin_amdgcn_mfma_f32_16x16x32_bf16(ga1, pb1, az, 0, 0, 0);
    if (cq < 8) {
      #pragma unroll
      for (int r2 = 0; r2 < 4; r2++) {
        const int o = reg_o0 + r2;
        BFr[o][cq] = ar[r2] + biasL[0][o];
        BFz[o][cq] = az[r2] + biasL[1][o];
      }
    }
  }

  // ---- P1b: layer-0 r/z (+dir epilogue), write r0 B-frags, z max-reduce ----
  {
    const bf8_t ra0 = FRAG(M_R0, 0), ra1 = FRAG(M_R0, 1);
    const bf8_t za0 = FRAG(M_Z0, 0), za1 = FRAG(M_Z0, 1);
    float wdr[3][4], wdz[3][4];
    #pragma unroll
    for (int d = 0; d < 3; d++)
      #pragma unroll
      for (int r2 = 0; r2 < 4; r2++) {
        wdr[d][r2] = wdir[(0*3 + d)*64 + reg_o0 + r2];
        wdz[d][r2] = wdir[(1*3 + d)*64 + reg_o0 + r2];
      }
    const int kkv = reg_o0 >> 5, lp = ((reg_o0 & 31) >> 3)*16 + cq, j0 = reg_o0 & 7;
    #pragma unroll
    for (int ct = 0; ct < GQ; ct++) {
      const bf8_t fb0 = *(const bf8_t*)&featB[0][ct][lane][0];
      const bf8_t fb1 = *(const bf8_t*)&featB[1][ct][lane][0];
      f32x4 accr = __builtin_amdgcn_mfma_f32_16x16x32_bf16(ra0, fb0, zero4, 0, 0, 0);
      accr = __builtin_amdgcn_mfma_f32_16x16x32_bf16(ra1, fb1, accr, 0, 0, 0);
      f32x4 accz = __builtin_amdgcn_mfma_f32_16x16x32_bf16(za0, fb0, zero4, 0, 0, 0);
      accz = __builtin_amdgcn_mfma_f32_16x16x32_bf16(za1, fb1, accz, 0, 0, 0);
      const int m = ct*16 + cq;
      const float d0 = dirL[0][m], d1 = dirL[1][m], d2 = dirL[2][m];
      unsigned short rpk[4]; float zv[4];
      #pragma unroll
      for (int r2 = 0; r2 < 4; r2++) {
        const int o = reg_o0 + r2;
        float rv = accr[r2] + BFr[o][ct] + wdr[0][r2]*d0 + wdr[1][r2]*d1 + wdr[2][r2]*d2;
        rpk[r2] = f2bf(lrelu(rv));
        float zt = accz[r2] + BFz[o][ct] + wdz[0][r2]*d0 + wdz[1][r2]*d1 + wdz[2][r2]*d2;
        zv[r2] = lrelu(zt);
      }
      uint2 pk; pk.x = rpk[0] | ((unsigned)rpk[1] << 16); pk.y = rpk[2] | ((unsigned)rpk[3] << 16);
      *(uint2*)&rB[kkv][ct][lp][j0] = pk;
      #pragma unroll
      for (int r2 = 0; r2 < 4; r2++) {
        float vv = zv[r2];
        vv = fmaxf(vv, __shfl_xor(vv, 1));
        vv = fmaxf(vv, __shfl_xor(vv, 2));
        vv = fmaxf(vv, __shfl_xor(vv, 4));
        vv = fmaxf(vv, __shfl_xor(vv, 8));
        zv[r2] = vv;
      }
      if (cq == 0) {
        #pragma unroll
        for (int r2 = 0; r2 < 4; r2++) zmaxL[reg_o0 + r2][ct] = zv[r2];
      }
    }
  }
  __syncthreads();

  // ---- P2: r1 (hold r*p1 packed in regs), z1 ----
  uint2 rpK[GQ];
  float zg[4];
  {
    const bf8_t r1a0 = FRAG(M_R1, 0), r1a1 = FRAG(M_R1, 1);
    #pragma unroll
    for (int ct = 0; ct < GQ; ct++) {
      const bf8_t b0 = *(const bf8_t*)&rB[0][ct][lane][0];
      const bf8_t b1 = *(const bf8_t*)&rB[1][ct][lane][0];
      f32x4 acc = __builtin_amdgcn_mfma_f32_16x16x32_bf16(r1a0, b0, zero4, 0, 0, 0);
      acc = __builtin_amdgcn_mfma_f32_16x16x32_bf16(r1a1, b1, acc, 0, 0, 0);
      unsigned short pk4[4];
      #pragma unroll
      for (int r2 = 0; r2 < 4; r2++) {
        const int o = reg_o0 + r2;
        const float rg = sigm(acc[r2] + biasL[3][o]);
        pk4[r2] = f2bf(rg * p1f[o][ct]);
      }
      rpK[ct].x = pk4[0] | ((unsigned)pk4[1] << 16);
      rpK[ct].y = pk4[2] | ((unsigned)pk4[3] << 16);
    }
    const bf8_t z1a0 = FRAG(M_Z1, 0), z1a1 = FRAG(M_Z1, 1);
    const int qc = cq < 8 ? cq : 7;
    bf8_t zb0, zb1;
    #pragma unroll
    for (int j = 0; j < 8; j++) {
      zb0[j] = (short)f2bf(zmaxL[((lane >> 4) << 3) + j][qc]);
      zb1[j] = (short)f2bf(zmaxL[32 + ((lane >> 4) << 3) + j][qc]);
    }
    f32x4 az = __builtin_amdgcn_mfma_f32_16x16x32_bf16(z1a0, zb0, zero4, 0, 0, 0);
    az = __builtin_amdgcn_mfma_f32_16x16x32_bf16(z1a1, zb1, az, 0, 0, 0);
    #pragma unroll
    for (int r2 = 0; r2 < 4; r2++) zg[r2] = sigm(az[r2] + biasL[4][reg_o0 + r2]);
  }
  __syncthreads();

  // ---- P2b: overwrite rB with r*p1 ----
  {
    const int kkv = reg_o0 >> 5, lp = ((reg_o0 & 31) >> 3)*16 + cq, j0 = reg_o0 & 7;
    #pragma unroll
    for (int ct = 0; ct < GQ; ct++) *(uint2*)&rB[kkv][ct][lp][j0] = rpK[ct];
  }
  __syncthreads();

  // ---- P3: h0·feat + fro·(r*p1) (+dir), h max-reduce ----
  {
    const bf8_t h0a0 = FRAG(M_H0, 0), h0a1 = FRAG(M_H0, 1);
    const bf8_t foa0 = FRAG(M_FRO, 0), foa1 = FRAG(M_FRO, 1);
    float wdh[3][4];
    #pragma unroll
    for (int d = 0; d < 3; d++)
      #pragma unroll
      for (int r2 = 0; r2 < 4; r2++) wdh[d][r2] = wdir[(2*3 + d)*64 + reg_o0 + r2];
    #pragma unroll
    for (int ct = 0; ct < GQ; ct++) {
      const bf8_t fb0 = *(const bf8_t*)&featB[0][ct][lane][0];
      const bf8_t fb1 = *(const bf8_t*)&featB[1][ct][lane][0];
      const bf8_t rb0 = *(const bf8_t*)&rB[0][ct][lane][0];
      const bf8_t rb1 = *(const bf8_t*)&rB[1][ct][lane][0];
      f32x4 acc = __builtin_amdgcn_mfma_f32_16x16x32_bf16(h0a0, fb0, zero4, 0, 0, 0);
      acc = __builtin_amdgcn_mfma_f32_16x16x32_bf16(h0a1, fb1, acc, 0, 0, 0);
      acc = __builtin_amdgcn_mfma_f32_16x16x32_bf16(foa0, rb0, acc, 0, 0, 0);
      acc = __builtin_amdgcn_mfma_f32_16x16x32_bf16(foa1, rb1, acc, 0, 0, 0);
      const int m = ct*16 + cq;
      const float d0 = dirL[0][m], d1 = dirL[1][m], d2 = dirL[2][m];
      float hv[4];
      #pragma unroll
      for (int r2 = 0; r2 < 4; r2++) {
        const int o = reg_o0 + r2;
        hv[r2] = lrelu(acc[r2] + biasL[2][o] + wdh[0][r2]*d0 + wdh[1][r2]*d1 + wdh[2][r2]*d2);
      }
      #pragma unroll
      for (int r2 = 0; r2 < 4; r2++) {
        float vv = hv[r2];
        vv = fmaxf(vv, __shfl_xor(vv, 1));
        vv = fmaxf(vv, __shfl_xor(vv, 2));
        vv = fmaxf(vv, __shfl_xor(vv, 4));
        vv = fmaxf(vv, __shfl_xor(vv, 8));
        hv[r2] = vv;
      }
      if (cq == 0) {
        #pragma unroll
        for (int r2 = 0; r2 < 4; r2++) hmaxL[reg_o0 + r2][ct] = hv[r2];
      }
    }
  }
  __syncthreads();

  // ---- P4: h1, final blend ----
  {
    const bf8_t h1a0 = FRAG(M_H1, 0), h1a1 = FRAG(M_H1, 1);
    const int qc = cq < 8 ? cq : 7;
    bf8_t hb0, hb1;
    #pragma unroll
    for (int j = 0; j < 8; j++) {
      hb0[j] = (short)f2bf(hmaxL[((lane >> 4) << 3) + j][qc]);
      hb1[j] = (short)f2bf(hmaxL[32 + ((lane >> 4) << 3) + j][qc]);
    }
    f32x4 ah = __builtin_amdgcn_mfma_f32_16x16x32_bf16(h1a0, hb0, zero4, 0, 0, 0);
    ah = __builtin_amdgcn_mfma_f32_16x16x32_bf16(h1a1, hb1, ah, 0, 0, 0);
    if (cq < 8) {
      #pragma unroll
      for (int r2 = 0; r2 < 4; r2++) {
        const int o = reg_o0 + r2;
        const float hg = tanh_(ah[r2] + biasL[5][o]);
        obuf[o][cq] = (1.f - zg[r2])*p1f[o][cq] + zg[r2]*hg;
      }
    }
  }
  __syncthreads();
  if (tid < 128) {
    const int c = tid >> 1, q4 = (tid & 1)*4;
    *(float4*)(out + ((size_t)(b*CC + c))*N1S + n0 + q4) = *(float4*)&obuf[c][q4];
  }
}

extern "C" void kernel_launch(void* const* d_in, const int* in_sizes, int n_in,
                              void* d_out, int out_size, void* d_ws, size_t ws_size,
                              hipStream_t stream) {
  const float* xyz1    = (const float*)d_in[0];
  const float* xyz2    = (const float*)d_in[1];
  const float* points1 = (const float*)d_in[2];
  const float* points2 = (const float*)d_in[3];
  const float* w_r0 = (const float*)d_in[4];
  const float* b_r0 = (const float*)d_in[5];
  const float* w_r1 = (const float*)d_in[6];
  const float* b_r1 = (const float*)d_in[7];
  const float* w_z0 = (const float*)d_in[8];
  const float* b_z0 = (const float*)d_in[9];
  const float* w_z1 = (const float*)d_in[10];
  const float* b_z1 = (const float*)d_in[11];
  const float* w_h0 = (const float*)d_in[12];
  const float* b_h0 = (const float*)d_in[13];
  const float* w_h1 = (const float*)d_in[14];
  const float* b_h1 = (const float*)d_in[15];
  const float* w_fr  = (const float*)d_in[16];
  const float* w_fz  = (const float*)d_in[17];
  const float* w_fro = (const float*)d_in[18];
  float* out = (float*)d_out;

  short*  wa   = (short*)d_ws;
  float*  wdir = (float*)((char*)d_ws + WDIR_OFF);
  float4* xp   = (float4*)((char*)d_ws + XP_OFF);
  int*    kidx = (int*)((char*)d_ws + KIDX_OFF);
  unsigned short* p2b = (unsigned short*)((char*)d_ws + P2B_OFF);

  prep_wA<<<16, 256, 0, stream>>>(w_r0, w_z0, w_h0, w_r1, w_z1, w_h1,
                                  w_fr, w_fz, w_fro, wa, wdir);
  pack_xyz2<<<64, 256, 0, stream>>>(xyz2, xp);
  transpose_p2<<<dim3(N2S/64, NB), dim3(256), 0, stream>>>(points2, p2b);

  knn_kernel<<<2048, 256, 0, stream>>>(xyz1, xp, kidx);

  gates_kernel<<<1024, 256, 0, stream>>>(
      xyz1, xyz2, points1, p2b, kidx, wa, wdir,
      b_r0, b_z0, b_h0, b_r1, b_z1, b_h1, out);
}

// Round 10
// 192.216 us; speedup vs baseline: 1.0551x; 1.0362x over previous
//
#include <hip/hip_runtime.h>
#include <math.h>

typedef __attribute__((ext_vector_type(8))) short bf8_t;
typedef __attribute__((ext_vector_type(4))) float f32x4;

#define NB   2
#define N1S  4096
#define N2S  8192
#define CC   64
#define KK   16
#define GQ   4

// mat ids in wA
#define M_R0 0
#define M_Z0 1
#define M_H0 2
#define M_R1 3
#define M_Z1 4
#define M_H1 5
#define M_FR 6
#define M_FZ 7
#define M_FRO 8

// ---- ws layout (bytes) ----
#define WA_SHORTS   (9*4*2*64*8)                 // 36864 shorts = 73728 B
#define WDIR_OFF    (WA_SHORTS*2)                // 73728
#define WDIR_FLOATS (3*3*64)                     // 576
#define XP_OFF      (WDIR_OFF + WDIR_FLOATS*4)   // 76032 (16B aligned)
#define XP_BYTES    (NB*N2S*16)                  // 262144
#define KIDX_OFF    (XP_OFF + XP_BYTES)          // 338176
#define KIDX_BYTES  (NB*N1S*KK*4)                // 524288
#define P2B_OFF     (KIDX_OFF + KIDX_BYTES)      // 862464 (16B aligned)
#define P2B_BYTES   ((size_t)NB*N2S*CC*2)        // 2 MiB (bf16)

__device__ __forceinline__ float lrelu(float v){ return v > 0.f ? v : 0.1f*v; }
__device__ __forceinline__ float sigm(float v){ return 1.f/(1.f + __expf(-v)); }
__device__ __forceinline__ float tanh_(float v){ return 1.f - 2.f/(__expf(2.f*v) + 1.f); }
__device__ __forceinline__ unsigned short f2bf(float f){
  union { float f; unsigned u; } v; v.f = f;
  unsigned r = v.u + 0x7FFF + ((v.u >> 16) & 1);
  return (unsigned short)(r >> 16);
}

// ---------------- fused prep: p2 transpose->bf16 (blocks 0..255) | weight A-frag pack (256..271).
// Both parts are bitwise-deterministic (copies + integer-rounded f2bf) — no FP-contraction
// sensitivity, so fusing them cannot perturb value-critical codegen. pack_xyz2 stays separate. ----
__global__ __launch_bounds__(256) void prep_misc(
    const float* __restrict__ points2,
    const float* __restrict__ r0, const float* __restrict__ z0, const float* __restrict__ h0,
    const float* __restrict__ r1, const float* __restrict__ z1, const float* __restrict__ h1,
    const float* __restrict__ fr, const float* __restrict__ fz, const float* __restrict__ fro,
    short* __restrict__ wa, float* __restrict__ wdir, unsigned short* __restrict__ p2b)
{
  __shared__ float t[64][65];
  const int blk = blockIdx.x;
  if (blk < 256) {
    // points2 [B,C,N2] f32 -> [B,N2,C] bf16
    const int b = blk >> 7; const int j0 = (blk & 127)*64;
    const int tx = threadIdx.x & 63; const int r4 = threadIdx.x >> 6;
    #pragma unroll
    for (int c = r4; c < 64; c += 4) t[c][tx] = points2[((size_t)b*CC + c)*N2S + j0 + tx];
    __syncthreads();
    #pragma unroll
    for (int j = r4; j < 64; j += 4) p2b[((size_t)b*N2S + j0 + j)*CC + tx] = f2bf(t[tx][j]);
  } else {
    // pack 9 weight matrices into A-fragment layout + dir weights
    const float* W[9] = {r0, z0, h0, r1, z1, h1, fr, fz, fro};
    const int Ks[9]   = {67, 67, 67, 64, 64, 64, 64, 64, 64};
    for (int i = (blk - 256)*256 + threadIdx.x; i < WA_SHORTS; i += 16*256) {
      const int j = i & 7, l = (i >> 3) & 63, kk = (i >> 9) & 1, r = (i >> 10) & 3, mat = i >> 12;
      const int row = r*16 + (l & 15);
      const int c = kk*32 + ((l >> 4) << 3) + j;
      wa[i] = (short)f2bf(W[mat][row*Ks[mat] + c]);
    }
    for (int i = (blk - 256)*256 + threadIdx.x; i < WDIR_FLOATS; i += 16*256) {
      const int g = i / 192, rem = i % 192, d = rem / 64, o = rem & 63;
      wdir[i] = W[g][o*67 + 64 + d];
    }
  }
}

// ---------------- pack xyz2 as float4(x,y,z,|p|^2)  [BYTE-IDENTICAL to r9 — ulp-critical] ----------------
__global__ __launch_bounds__(256) void pack_xyz2(const float* __restrict__ xyz2, float4* __restrict__ xp){
  const int i = blockIdx.x*256 + threadIdx.x;     // 0 .. 16383
  const int b = i >> 13, j = i & (N2S-1);
  const float x = xyz2[((size_t)(b*3+0))*N2S + j];
  const float y = xyz2[((size_t)(b*3+1))*N2S + j];
  const float z = xyz2[((size_t)(b*3+2))*N2S + j];
  xp[i] = make_float4(x, y, z, (x*x + y*y) + z*z);
}

// ---------------- KNN  [BYTE-IDENTICAL to r9 — ulp-critical selection path] ----------------
__global__ __launch_bounds__(256) void knn_kernel(
    const float* __restrict__ xyz1, const float4* __restrict__ xp, int* __restrict__ idxout)
{
  __shared__ float pdL[4][2][16];
  __shared__ int   piL[4][2][16];
  const int tid = threadIdx.x, w = tid >> 6, lane = tid & 63, grp = lane >> 4;
  const int qbase = blockIdx.x*4;                  // 4 queries/block; never crosses batch
  const int b = qbase >> 12;
  const int q0 = qbase + (w >> 1)*2;               // this wave's first query
  const int half = w & 1;
  const int hbase = half*(N2S/2);
  const float4* __restrict__ X = xp + (b << 13);
  float qx[2], qy[2], qz[2], s1[2], kth[2], kappa[2], m[2];
  #pragma unroll
  for (int g = 0; g < 2; g++) {
    const int n = (q0 + g) & (N1S-1);
    qx[g] = xyz1[((size_t)(b*3+0))*N1S + n];
    qy[g] = xyz1[((size_t)(b*3+1))*N1S + n];
    qz[g] = xyz1[((size_t)(b*3+2))*N1S + n];
    s1[g] = (qx[g]*qx[g] + qy[g]*qy[g]) + qz[g]*qz[g];
    kth[g] = INFINITY; m[g] = INFINITY;
  }

  // ---- pass 1: per-lane minima over this half's private partitions (L2-streamed).
  // Values ONLY form the kappa bound; pass 2 + guard make the set exact regardless. ----
  #pragma unroll 2
  for (int c0 = 0; c0 < N2S/2; c0 += 256) {
    const float4 v0 = X[hbase + c0 + lane];
    const float4 v1 = X[hbase + c0 + 64 + lane];
    const float4 v2 = X[hbase + c0 + 128 + lane];
    const float4 v3 = X[hbase + c0 + 192 + lane];
    #pragma unroll
    for (int g = 0; g < 2; g++) {
      const float d0 = (s1[g] + v0.w) - 2.f*((qx[g]*v0.x + qy[g]*v0.y) + qz[g]*v0.z);
      const float d1 = (s1[g] + v1.w) - 2.f*((qx[g]*v1.x + qy[g]*v1.y) + qz[g]*v1.z);
      const float d2 = (s1[g] + v2.w) - 2.f*((qx[g]*v2.x + qy[g]*v2.y) + qz[g]*v2.z);
      const float d3 = (s1[g] + v3.w) - 2.f*((qx[g]*v3.x + qy[g]*v3.y) + qz[g]*v3.z);
      m[g] = fminf(m[g], fminf(fminf(d0, d1), fminf(d2, d3)));
    }
  }
  // kappa[g] = 17th smallest lane-min (> this half's true d16, or the guard fires)
  #pragma unroll
  for (int g = 0; g < 2; g++) {
    float v = m[g];
    #pragma unroll
    for (int k = 2; k <= 64; k <<= 1) {
      #pragma unroll
      for (int j = k >> 1; j > 0; j >>= 1) {
        const float pv = __shfl_xor(v, j);
        const bool up = ((lane & k) == 0);
        const bool keepmin = up ? ((lane & j) == 0) : ((lane & j) != 0);
        v = keepmin ? fminf(v, pv) : fmaxf(v, pv);
      }
    }
    kappa[g] = __shfl(v, 16);
  }

  // ---- pass 2: exact streaming insert over this half, gated by min(kth, kappa) ----
  float listd = INFINITY; int listi = 0;
  #pragma unroll 2
  for (int c0 = 0; c0 < N2S/2; c0 += 64) {
    const float4 v = X[hbase + c0 + lane];
    #pragma unroll
    for (int g = 0; g < 2; g++) {
      // EXACT same distance expression as r3..r9 (keeps neighbor sets identical)
      const float d = (s1[g] + v.w) - 2.f*((qx[g]*v.x + qy[g]*v.y) + qz[g]*v.z);
      unsigned long long vote = __ballot(d < fminf(kth[g], kappa[g]));
      while (vote) {
        const int src = (int)__builtin_ctzll(vote);
        vote &= vote - 1;
        const float dv = __shfl(d, src);
        if (dv < kth[g]) {                       // uniform
          const int iv = hbase + c0 + src;
          const float ud = __shfl_up(listd, 1);
          const int   ui = __shfl_up(listi, 1);
          const bool ing = (grp == g);
          const bool cm = ing && (dv < listd);   // strict < keeps lower index on ties
          const bool cp = cm && ((lane & 15) > 0) && (dv < ud);
          listd = cm ? (cp ? ud : dv) : listd;
          listi = cm ? (cp ? ui : iv) : listi;
          kth[g] = __shfl(listd, g*16 + 15);
        }
      }
    }
  }

  // ---- exactness guard: if <16 found in this half, rescan the half unpruned ----
  {
    bool need = false;
    #pragma unroll
    for (int g = 0; g < 2; g++) need = need || (kth[g] == INFINITY);
    if (__builtin_expect(need, 0)) {
      #pragma unroll
      for (int g = 0; g < 2; g++) {
        if (kth[g] == INFINITY) {                // uniform
          if (grp == g) { listd = INFINITY; listi = 0; }
          float kk2 = INFINITY;
          for (int c0 = 0; c0 < N2S/2; c0 += 64) {
            const float4 v = X[hbase + c0 + lane];
            const float d = (s1[g] + v.w) - 2.f*((qx[g]*v.x + qy[g]*v.y) + qz[g]*v.z);
            unsigned long long vote = __ballot(d < kk2);
            while (vote) {
              const int src = (int)__builtin_ctzll(vote);
              vote &= vote - 1;
              const float dv = __shfl(d, src);
              if (dv < kk2) {
                const int iv = hbase + c0 + src;
                const float ud = __shfl_up(listd, 1);
                const int   ui = __shfl_up(listi, 1);
                const bool ing = (grp == g);
                const bool cm = ing && (dv < listd);
                const bool cp = cm && ((lane & 15) > 0) && (dv < ud);
                listd = cm ? (cp ? ud : dv) : listd;
                listi = cm ? (cp ? ui : iv) : listi;
                kk2 = __shfl(listd, g*16 + 15);
              }
            }
          }
        }
      }
    }
  }

  // ---- store per-half partial lists ----
  if (grp < 2) {
    const int qi = (w >> 1)*2 + grp;
    pdL[qi][half][lane & 15] = listd;
    piL[qi][half][lane & 15] = listi;
  }
  __syncthreads();

  // ---- merge: wave w merges query qbase+w via 64-lane bitonic sort on (d, idx) ----
  {
    float d = (lane < 32) ? pdL[w][lane >> 4][lane & 15] : INFINITY;
    int   i = (lane < 32) ? piL[w][lane >> 4][lane & 15] : 0x7fffffff;
    #pragma unroll
    for (int k = 2; k <= 64; k <<= 1) {
      #pragma unroll
      for (int j = k >> 1; j > 0; j >>= 1) {
        const float pdv = __shfl_xor(d, j);
        const int   piv = __shfl_xor(i, j);
        const bool keepmin = (((lane & k) == 0) == ((lane & j) == 0));
        const bool ownless = (d < pdv) || (d == pdv && i < piv);
        const bool takeown = keepmin ? ownless : !ownless;
        d = takeown ? d : pdv;
        i = takeown ? i : piv;
      }
    }
    if (lane < KK) idxout[(size_t)(qbase + w)*KK + lane] = i;
  }
}

// ---------------- gates: MFMA pipeline, now GQ=4 queries / block, 2048 blocks (~26 KB LDS,
// 6 blocks/CU vs 4 before) — per-query arithmetic identical to the GQ=8 version. ----------------
#define FRAG(mat, kk) (*(const bf8_t*)(wA + (((mat)*4 + w)*2 + (kk))*512 + lane*8))

__global__ __launch_bounds__(256) void gates_kernel(
    const float* __restrict__ xyz1, const float* __restrict__ xyz2,
    const float* __restrict__ points1, const unsigned short* __restrict__ p2b,
    const int* __restrict__ kidx, const short* __restrict__ wA,
    const float* __restrict__ wdir,
    const float* __restrict__ b_r0, const float* __restrict__ b_z0,
    const float* __restrict__ b_h0, const float* __restrict__ b_r1,
    const float* __restrict__ b_z1, const float* __restrict__ b_h1,
    float* __restrict__ out)
{
  __shared__ __align__(16) short featB[2][GQ][64][8];  // p2 channels, B-frag packed (8 KB)
  __shared__ __align__(16) short rB[2][GQ][64][8];     // r0 acts, then r*p1 in-place (8 KB)
  __shared__ __align__(16) float p1f[64][GQ];
  __shared__ __align__(16) short p1B[2][64][8];
  __shared__ float BFr[64][GQ], BFz[64][GQ];
  __shared__ float zmaxL[64][GQ], hmaxL[64][GQ];
  __shared__ float biasL[6][64];
  __shared__ float dirL[3][GQ*KK];
  __shared__ __align__(16) float obuf[64][GQ];

  const int tid = threadIdx.x;
  const int w = tid >> 6, lane = tid & 63;
  const int b  = blockIdx.x >> 10;
  const int n0 = (blockIdx.x & 1023) * GQ;
  const int cq = lane & 15;                       // C col within tile (= query q)
  const int reg_o0 = w*16 + ((lane >> 4) << 2);   // first of this lane's 4 C rows
  const f32x4 zero4 = {0.f, 0.f, 0.f, 0.f};

  // ---- P0a ----
  for (int i = tid; i < 6*64; i += 256) {
    const int a = i >> 6, o = i & 63;
    const float* bp = (a==0)?b_r0:(a==1)?b_z0:(a==2)?b_h0:(a==3)?b_r1:(a==4)?b_z1:b_h1;
    biasL[a][o] = bp[o];
  }
  if (tid < 64) {
    const float* sp = points1 + ((size_t)(b*CC + tid))*N1S + n0;
    *(float4*)&p1f[tid][0] = ((const float4*)sp)[0];
  }
  ((unsigned long long*)&p1B[0][0][0])[tid] = 0ULL;   // zero 2048 B
  if (tid < 64) {                                     // dir channels (GQ*KK = 64)
    const int m = tid, qg = n0 + (m >> 4);
    const int j = kidx[(size_t)((b << 12) + qg)*KK + (m & 15)];
    #pragma unroll
    for (int d = 0; d < 3; d++)
      dirL[d][m] = xyz2[((size_t)(b*3+d))*N2S + j] - xyz1[((size_t)(b*3+d))*N1S + qg];
  }
  {                                                   // p2 feature gather (bf16) -> featB (B-frag packed)
    const int m = tid >> 2, qt = tid & 3;             // row m of 64, quarter qt (16 channels)
    const int ct = m >> 4;
    const int qg = n0 + ct;
    const int j = kidx[(size_t)((b << 12) + qg)*KK + (m & 15)];
    const uint4* __restrict__ src = (const uint4*)(p2b + (((size_t)(b << 13) + j)*CC + qt*16));
    const uint4 u0 = src[0], u1 = src[1];
    *(uint4*)&featB[qt >> 1][ct][((qt & 1)*2 + 0)*16 + (m & 15)][0] = u0;
    *(uint4*)&featB[qt >> 1][ct][((qt & 1)*2 + 1)*16 + (m & 15)][0] = u1;
  }
  __syncthreads();

  // ---- P0b: p1 as B-frag (cols 0..3 valid, rest zero) ----
  {
    const int s0 = tid*4;
    const int j0 = s0 & 7, l = (s0 >> 3) & 63, kk = s0 >> 9;
    const int q = l & 15;
    if (q < GQ) {
      unsigned short t0[4];
      #pragma unroll
      for (int jj = 0; jj < 4; jj++)
        t0[jj] = f2bf(p1f[kk*32 + ((l >> 4) << 3) + j0 + jj][q]);
      uint2 pk; pk.x = t0[0] | ((unsigned)t0[1] << 16); pk.y = t0[2] | ((unsigned)t0[3] << 16);
      *(uint2*)&p1B[kk][l][j0] = pk;
    }
  }
  __syncthreads();

  // ---- P1: fuse GEMMs -> BFr/BFz ----
  {
    const bf8_t fa0 = FRAG(M_FR, 0), fa1 = FRAG(M_FR, 1);
    const bf8_t ga0 = FRAG(M_FZ, 0), ga1 = FRAG(M_FZ, 1);
    const bf8_t pb0 = *(const bf8_t*)&p1B[0][lane][0];
    const bf8_t pb1 = *(const bf8_t*)&p1B[1][lane][0];
    f32x4 ar = __builtin_amdgcn_mfma_f32_16x16x32_bf16(fa0, pb0, zero4, 0, 0, 0);
    ar = __builtin_amdgcn_mfma_f32_16x16x32_bf16(fa1, pb1, ar, 0, 0, 0);
    f32x4 az = __builtin_amdgcn_mfma_f32_16x16x32_bf16(ga0, pb0, zero4, 0, 0, 0);
    az = __builtin_amdgcn_mfma_f32_16x16x32_bf16(ga1, pb1, az, 0, 0, 0);
    if (cq < GQ) {
      #pragma unroll
      for (int r2 = 0; r2 < 4; r2++) {
        const int o = reg_o0 + r2;
        BFr[o][cq] = ar[r2] + biasL[0][o];
        BFz[o][cq] = az[r2] + biasL[1][o];
      }
    }
  }

  // ---- P1b: layer-0 r/z (+dir epilogue), write r0 B-frags, z max-reduce ----
  {
    const bf8_t ra0 = FRAG(M_R0, 0), ra1 = FRAG(M_R0, 1);
    const bf8_t za0 = FRAG(M_Z0, 0), za1 = FRAG(M_Z0, 1);
    float wdr[3][4], wdz[3][4];
    #pragma unroll
    for (int d = 0; d < 3; d++)
      #pragma unroll
      for (int r2 = 0; r2 < 4; r2++) {
        wdr[d][r2] = wdir[(0*3 + d)*64 + reg_o0 + r2];
        wdz[d][r2] = wdir[(1*3 + d)*64 + reg_o0 + r2];
      }
    const int kkv = reg_o0 >> 5, lp = ((reg_o0 & 31) >> 3)*16 + cq, j0 = reg_o0 & 7;
    #pragma unroll
    for (int ct = 0; ct < GQ; ct++) {
      const bf8_t fb0 = *(const bf8_t*)&featB[0][ct][lane][0];
      const bf8_t fb1 = *(const bf8_t*)&featB[1][ct][lane][0];
      f32x4 accr = __builtin_amdgcn_mfma_f32_16x16x32_bf16(ra0, fb0, zero4, 0, 0, 0);
      accr = __builtin_amdgcn_mfma_f32_16x16x32_bf16(ra1, fb1, accr, 0, 0, 0);
      f32x4 accz = __builtin_amdgcn_mfma_f32_16x16x32_bf16(za0, fb0, zero4, 0, 0, 0);
      accz = __builtin_amdgcn_mfma_f32_16x16x32_bf16(za1, fb1, accz, 0, 0, 0);
      const int m = ct*16 + cq;
      const float d0 = dirL[0][m], d1 = dirL[1][m], d2 = dirL[2][m];
      unsigned short rpk[4]; float zv[4];
      #pragma unroll
      for (int r2 = 0; r2 < 4; r2++) {
        const int o = reg_o0 + r2;
        float rv = accr[r2] + BFr[o][ct] + wdr[0][r2]*d0 + wdr[1][r2]*d1 + wdr[2][r2]*d2;
        rpk[r2] = f2bf(lrelu(rv));
        float zt = accz[r2] + BFz[o][ct] + wdz[0][r2]*d0 + wdz[1][r2]*d1 + wdz[2][r2]*d2;
        zv[r2] = lrelu(zt);
      }
      uint2 pk; pk.x = rpk[0] | ((unsigned)rpk[1] << 16); pk.y = rpk[2] | ((unsigned)rpk[3] << 16);
      *(uint2*)&rB[kkv][ct][lp][j0] = pk;
      #pragma unroll
      for (int r2 = 0; r2 < 4; r2++) {
        float vv = zv[r2];
        vv = fmaxf(vv, __shfl_xor(vv, 1));
        vv = fmaxf(vv, __shfl_xor(vv, 2));
        vv = fmaxf(vv, __shfl_xor(vv, 4));
        vv = fmaxf(vv, __shfl_xor(vv, 8));
        zv[r2] = vv;
      }
      if (cq == 0) {
        #pragma unroll
        for (int r2 = 0; r2 < 4; r2++) zmaxL[reg_o0 + r2][ct] = zv[r2];
      }
    }
  }
  __syncthreads();

  // ---- P2: r1 (hold r*p1 packed in regs), z1 ----
  uint2 rpK[GQ];
  float zg[4];
  {
    const bf8_t r1a0 = FRAG(M_R1, 0), r1a1 = FRAG(M_R1, 1);
    #pragma unroll
    for (int ct = 0; ct < GQ; ct++) {
      const bf8_t b0 = *(const bf8_t*)&rB[0][ct][lane][0];
      const bf8_t b1 = *(const bf8_t*)&rB[1][ct][lane][0];
      f32x4 acc = __builtin_amdgcn_mfma_f32_16x16x32_bf16(r1a0, b0, zero4, 0, 0, 0);
      acc = __builtin_amdgcn_mfma_f32_16x16x32_bf16(r1a1, b1, acc, 0, 0, 0);
      unsigned short pk4[4];
      #pragma unroll
      for (int r2 = 0; r2 < 4; r2++) {
        const int o = reg_o0 + r2;
        const float rg = sigm(acc[r2] + biasL[3][o]);
        pk4[r2] = f2bf(rg * p1f[o][ct]);
      }
      rpK[ct].x = pk4[0] | ((unsigned)pk4[1] << 16);
      rpK[ct].y = pk4[2] | ((unsigned)pk4[3] << 16);
    }
    const bf8_t z1a0 = FRAG(M_Z1, 0), z1a1 = FRAG(M_Z1, 1);
    const int qc = cq < GQ ? cq : (GQ-1);
    bf8_t zb0, zb1;
    #pragma unroll
    for (int j = 0; j < 8; j++) {
      zb0[j] = (short)f2bf(zmaxL[((lane >> 4) << 3) + j][qc]);
      zb1[j] = (short)f2bf(zmaxL[32 + ((lane >> 4) << 3) + j][qc]);
    }
    f32x4 az = __builtin_amdgcn_mfma_f32_16x16x32_bf16(z1a0, zb0, zero4, 0, 0, 0);
    az = __builtin_amdgcn_mfma_f32_16x16x32_bf16(z1a1, zb1, az, 0, 0, 0);
    #pragma unroll
    for (int r2 = 0; r2 < 4; r2++) zg[r2] = sigm(az[r2] + biasL[4][reg_o0 + r2]);
  }
  __syncthreads();

  // ---- P2b: overwrite rB with r*p1 ----
  {
    const int kkv = reg_o0 >> 5, lp = ((reg_o0 & 31) >> 3)*16 + cq, j0 = reg_o0 & 7;
    #pragma unroll
    for (int ct = 0; ct < GQ; ct++) *(uint2*)&rB[kkv][ct][lp][j0] = rpK[ct];
  }
  __syncthreads();

  // ---- P3: h0·feat + fro·(r*p1) (+dir), h max-reduce ----
  {
    const bf8_t h0a0 = FRAG(M_H0, 0), h0a1 = FRAG(M_H0, 1);
    const bf8_t foa0 = FRAG(M_FRO, 0), foa1 = FRAG(M_FRO, 1);
    float wdh[3][4];
    #pragma unroll
    for (int d = 0; d < 3; d++)
      #pragma unroll
      for (int r2 = 0; r2 < 4; r2++) wdh[d][r2] = wdir[(2*3 + d)*64 + reg_o0 + r2];
    #pragma unroll
    for (int ct = 0; ct < GQ; ct++) {
      const bf8_t fb0 = *(const bf8_t*)&featB[0][ct][lane][0];
      const bf8_t fb1 = *(const bf8_t*)&featB[1][ct][lane][0];
      const bf8_t rb0 = *(const bf8_t*)&rB[0][ct][lane][0];
      const bf8_t rb1 = *(const bf8_t*)&rB[1][ct][lane][0];
      f32x4 acc = __builtin_amdgcn_mfma_f32_16x16x32_bf16(h0a0, fb0, zero4, 0, 0, 0);
      acc = __builtin_amdgcn_mfma_f32_16x16x32_bf16(h0a1, fb1, acc, 0, 0, 0);
      acc = __builtin_amdgcn_mfma_f32_16x16x32_bf16(foa0, rb0, acc, 0, 0, 0);
      acc = __builtin_amdgcn_mfma_f32_16x16x32_bf16(foa1, rb1, acc, 0, 0, 0);
      const int m = ct*16 + cq;
      const float d0 = dirL[0][m], d1 = dirL[1][m], d2 = dirL[2][m];
      float hv[4];
      #pragma unroll
      for (int r2 = 0; r2 < 4; r2++) {
        const int o = reg_o0 + r2;
        hv[r2] = lrelu(acc[r2] + biasL[2][o] + wdh[0][r2]*d0 + wdh[1][r2]*d1 + wdh[2][r2]*d2);
      }
      #pragma unroll
      for (int r2 = 0; r2 < 4; r2++) {
        float vv = hv[r2];
        vv = fmaxf(vv, __shfl_xor(vv, 1));
        vv = fmaxf(vv, __shfl_xor(vv, 2));
        vv = fmaxf(vv, __shfl_xor(vv, 4));
        vv = fmaxf(vv, __shfl_xor(vv, 8));
        hv[r2] = vv;
      }
      if (cq == 0) {
        #pragma unroll
        for (int r2 = 0; r2 < 4; r2++) hmaxL[reg_o0 + r2][ct] = hv[r2];
      }
    }
  }
  __syncthreads();

  // ---- P4: h1, final blend ----
  {
    const bf8_t h1a0 = FRAG(M_H1, 0), h1a1 = FRAG(M_H1, 1);
    const int qc = cq < GQ ? cq : (GQ-1);
    bf8_t hb0, hb1;
    #pragma unroll
    for (int j = 0; j < 8; j++) {
      hb0[j] = (short)f2bf(hmaxL[((lane >> 4) << 3) + j][qc]);
      hb1[j] = (short)f2bf(hmaxL[32 + ((lane >> 4) << 3) + j][qc]);
    }
    f32x4 ah = __builtin_amdgcn_mfma_f32_16x16x32_bf16(h1a0, hb0, zero4, 0, 0, 0);
    ah = __builtin_amdgcn_mfma_f32_16x16x32_bf16(h1a1, hb1, ah, 0, 0, 0);
    if (cq < GQ) {
      #pragma unroll
      for (int r2 = 0; r2 < 4; r2++) {
        const int o = reg_o0 + r2;
        const float hg = tanh_(ah[r2] + biasL[5][o]);
        obuf[o][cq] = (1.f - zg[r2])*p1f[o][cq] + zg[r2]*hg;
      }
    }
  }
  __syncthreads();
  if (tid < 64)
    *(float4*)(out + ((size_t)(b*CC + tid))*N1S + n0) = *(float4*)&obuf[tid][0];
}

extern "C" void kernel_launch(void* const* d_in, const int* in_sizes, int n_in,
                              void* d_out, int out_size, void* d_ws, size_t ws_size,
                              hipStream_t stream) {
  const float* xyz1    = (const float*)d_in[0];
  const float* xyz2    = (const float*)d_in[1];
  const float* points1 = (const float*)d_in[2];
  const float* points2 = (const float*)d_in[3];
  const float* w_r0 = (const float*)d_in[4];
  const float* b_r0 = (const float*)d_in[5];
  const float* w_r1 = (const float*)d_in[6];
  const float* b_r1 = (const float*)d_in[7];
  const float* w_z0 = (const float*)d_in[8];
  const float* b_z0 = (const float*)d_in[9];
  const float* w_z1 = (const float*)d_in[10];
  const float* b_z1 = (const float*)d_in[11];
  const float* w_h0 = (const float*)d_in[12];
  const float* b_h0 = (const float*)d_in[13];
  const float* w_h1 = (const float*)d_in[14];
  const float* b_h1 = (const float*)d_in[15];
  const float* w_fr  = (const float*)d_in[16];
  const float* w_fz  = (const float*)d_in[17];
  const float* w_fro = (const float*)d_in[18];
  float* out = (float*)d_out;

  short*  wa   = (short*)d_ws;
  float*  wdir = (float*)((char*)d_ws + WDIR_OFF);
  float4* xp   = (float4*)((char*)d_ws + XP_OFF);
  int*    kidx = (int*)((char*)d_ws + KIDX_OFF);
  unsigned short* p2b = (unsigned short*)((char*)d_ws + P2B_OFF);

  prep_misc<<<272, 256, 0, stream>>>(points2,
                                     w_r0, w_z0, w_h0, w_r1, w_z1, w_h1,
                                     w_fr, w_fz, w_fro, wa, wdir, p2b);
  pack_xyz2<<<64, 256, 0, stream>>>(xyz2, xp);

  knn_kernel<<<2048, 256, 0, stream>>>(xyz1, xp, kidx);

  gates_kernel<<<2048, 256, 0, stream>>>(
      xyz1, xyz2, points1, p2b, kidx, wa, wdir,
      b_r0, b_z0, b_h0, b_r1, b_z1, b_h1, out);
}

// Round 11
// 189.988 us; speedup vs baseline: 1.0674x; 1.0117x over previous
//
#include <hip/hip_runtime.h>
#include <math.h>

typedef __attribute__((ext_vector_type(8))) short bf8_t;
typedef __attribute__((ext_vector_type(4))) float f32x4;

#define NB   2
#define N1S  4096
#define N2S  8192
#define CC   64
#define KK   16
#define GQ   4

// mat ids in wA
#define M_R0 0
#define M_Z0 1
#define M_H0 2
#define M_R1 3
#define M_Z1 4
#define M_H1 5
#define M_FR 6
#define M_FZ 7
#define M_FRO 8

// ---- ws layout (bytes) ----
#define WA_SHORTS   (9*4*2*64*8)                 // 36864 shorts = 73728 B
#define WDIR_OFF    (WA_SHORTS*2)                // 73728
#define WDIR_FLOATS (3*3*64)                     // 576
#define XP_OFF      (WDIR_OFF + WDIR_FLOATS*4)   // 76032 (16B aligned)
#define XP_BYTES    (NB*N2S*16)                  // 262144
#define P2B_OFF     (XP_OFF + XP_BYTES)          // 338176 (16B aligned)
#define P2B_BYTES   ((size_t)NB*N2S*CC*2)        // 2 MiB (bf16)

__device__ __forceinline__ float lrelu(float v){ return v > 0.f ? v : 0.1f*v; }
__device__ __forceinline__ float sigm(float v){ return 1.f/(1.f + __expf(-v)); }
__device__ __forceinline__ float tanh_(float v){ return 1.f - 2.f/(__expf(2.f*v) + 1.f); }
__device__ __forceinline__ unsigned short f2bf(float f){
  union { float f; unsigned u; } v; v.f = f;
  unsigned r = v.u + 0x7FFF + ((v.u >> 16) & 1);
  return (unsigned short)(r >> 16);
}

// ---------------- fused prep: p2 transpose->bf16 (blocks 0..255) | weight A-frag pack (256..271) ----
__global__ __launch_bounds__(256) void prep_misc(
    const float* __restrict__ points2,
    const float* __restrict__ r0, const float* __restrict__ z0, const float* __restrict__ h0,
    const float* __restrict__ r1, const float* __restrict__ z1, const float* __restrict__ h1,
    const float* __restrict__ fr, const float* __restrict__ fz, const float* __restrict__ fro,
    short* __restrict__ wa, float* __restrict__ wdir, unsigned short* __restrict__ p2b)
{
  __shared__ float t[64][65];
  const int blk = blockIdx.x;
  if (blk < 256) {
    // points2 [B,C,N2] f32 -> [B,N2,C] bf16
    const int b = blk >> 7; const int j0 = (blk & 127)*64;
    const int tx = threadIdx.x & 63; const int r4 = threadIdx.x >> 6;
    #pragma unroll
    for (int c = r4; c < 64; c += 4) t[c][tx] = points2[((size_t)b*CC + c)*N2S + j0 + tx];
    __syncthreads();
    #pragma unroll
    for (int j = r4; j < 64; j += 4) p2b[((size_t)b*N2S + j0 + j)*CC + tx] = f2bf(t[tx][j]);
  } else {
    // pack 9 weight matrices into A-fragment layout + dir weights
    const float* W[9] = {r0, z0, h0, r1, z1, h1, fr, fz, fro};
    const int Ks[9]   = {67, 67, 67, 64, 64, 64, 64, 64, 64};
    for (int i = (blk - 256)*256 + threadIdx.x; i < WA_SHORTS; i += 16*256) {
      const int j = i & 7, l = (i >> 3) & 63, kk = (i >> 9) & 1, r = (i >> 10) & 3, mat = i >> 12;
      const int row = r*16 + (l & 15);
      const int c = kk*32 + ((l >> 4) << 3) + j;
      wa[i] = (short)f2bf(W[mat][row*Ks[mat] + c]);
    }
    for (int i = (blk - 256)*256 + threadIdx.x; i < WDIR_FLOATS; i += 16*256) {
      const int g = i / 192, rem = i % 192, d = rem / 64, o = rem & 63;
      wdir[i] = W[g][o*67 + 64 + d];
    }
  }
}

// ---------------- pack xyz2 as float4(x,y,z,|p|^2)  [BYTE-IDENTICAL — ulp-critical] ----------------
__global__ __launch_bounds__(256) void pack_xyz2(const float* __restrict__ xyz2, float4* __restrict__ xp){
  const int i = blockIdx.x*256 + threadIdx.x;     // 0 .. 16383
  const int b = i >> 13, j = i & (N2S-1);
  const float x = xyz2[((size_t)(b*3+0))*N2S + j];
  const float y = xyz2[((size_t)(b*3+1))*N2S + j];
  const float z = xyz2[((size_t)(b*3+2))*N2S + j];
  xp[i] = make_float4(x, y, z, (x*x + y*y) + z*z);
}

// ---------------- fused KNN + gates: block = 4 queries.
// Phase A (verbatim r10 knn): wave w scans candidate half (w&1) for query pair (w>>1)*2+{0,1};
// per-half two-pass (kappa prune + exact gated insert + guard); bitonic merge -> kidxL in LDS.
// Phase B (verbatim r10 gates, kidx reads from LDS): MFMA gate stack for the same 4 queries. ----
#define FRAG(mat, kk) (*(const bf8_t*)(wA + (((mat)*4 + w)*2 + (kk))*512 + lane*8))

__global__ __launch_bounds__(256) void knn_gates_kernel(
    const float* __restrict__ xyz1, const float4* __restrict__ xp,
    const float* __restrict__ xyz2, const float* __restrict__ points1,
    const unsigned short* __restrict__ p2b, const short* __restrict__ wA,
    const float* __restrict__ wdir,
    const float* __restrict__ b_r0, const float* __restrict__ b_z0,
    const float* __restrict__ b_h0, const float* __restrict__ b_r1,
    const float* __restrict__ b_z1, const float* __restrict__ b_h1,
    float* __restrict__ out)
{
  // knn LDS
  __shared__ float pdL[4][2][16];
  __shared__ int   piL[4][2][16];
  __shared__ int   kidxL[4][16];
  // gates LDS
  __shared__ __align__(16) short featB[2][GQ][64][8];
  __shared__ __align__(16) short rB[2][GQ][64][8];
  __shared__ __align__(16) float p1f[64][GQ];
  __shared__ __align__(16) short p1B[2][64][8];
  __shared__ float BFr[64][GQ], BFz[64][GQ];
  __shared__ float zmaxL[64][GQ], hmaxL[64][GQ];
  __shared__ float biasL[6][64];
  __shared__ float dirL[3][GQ*KK];
  __shared__ __align__(16) float obuf[64][GQ];

  const int tid = threadIdx.x, w = tid >> 6, lane = tid & 63, grp = lane >> 4;
  const int b  = blockIdx.x >> 10;
  const int n0 = (blockIdx.x & 1023) * GQ;
  const int qbase = blockIdx.x*4;                  // == (b<<12) + n0; never crosses batch

  // ================= Phase A: KNN (statement text verbatim r10) =================
  {
    const int q0 = qbase + (w >> 1)*2;             // this wave's first query
    const int half = w & 1;
    const int hbase = half*(N2S/2);
    const float4* __restrict__ X = xp + (b << 13);
    float qx[2], qy[2], qz[2], s1[2], kth[2], kappa[2], m[2];
    #pragma unroll
    for (int g = 0; g < 2; g++) {
      const int n = (q0 + g) & (N1S-1);
      qx[g] = xyz1[((size_t)(b*3+0))*N1S + n];
      qy[g] = xyz1[((size_t)(b*3+1))*N1S + n];
      qz[g] = xyz1[((size_t)(b*3+2))*N1S + n];
      s1[g] = (qx[g]*qx[g] + qy[g]*qy[g]) + qz[g]*qz[g];
      kth[g] = INFINITY; m[g] = INFINITY;
    }

    // ---- pass 1: per-lane minima over this half's private partitions (L2-streamed) ----
    #pragma unroll 2
    for (int c0 = 0; c0 < N2S/2; c0 += 256) {
      const float4 v0 = X[hbase + c0 + lane];
      const float4 v1 = X[hbase + c0 + 64 + lane];
      const float4 v2 = X[hbase + c0 + 128 + lane];
      const float4 v3 = X[hbase + c0 + 192 + lane];
      #pragma unroll
      for (int g = 0; g < 2; g++) {
        const float d0 = (s1[g] + v0.w) - 2.f*((qx[g]*v0.x + qy[g]*v0.y) + qz[g]*v0.z);
        const float d1 = (s1[g] + v1.w) - 2.f*((qx[g]*v1.x + qy[g]*v1.y) + qz[g]*v1.z);
        const float d2 = (s1[g] + v2.w) - 2.f*((qx[g]*v2.x + qy[g]*v2.y) + qz[g]*v2.z);
        const float d3 = (s1[g] + v3.w) - 2.f*((qx[g]*v3.x + qy[g]*v3.y) + qz[g]*v3.z);
        m[g] = fminf(m[g], fminf(fminf(d0, d1), fminf(d2, d3)));
      }
    }
    // kappa[g] = 17th smallest lane-min (> this half's true d16, or the guard fires)
    #pragma unroll
    for (int g = 0; g < 2; g++) {
      float v = m[g];
      #pragma unroll
      for (int k = 2; k <= 64; k <<= 1) {
        #pragma unroll
        for (int j = k >> 1; j > 0; j >>= 1) {
          const float pv = __shfl_xor(v, j);
          const bool up = ((lane & k) == 0);
          const bool keepmin = up ? ((lane & j) == 0) : ((lane & j) != 0);
          v = keepmin ? fminf(v, pv) : fmaxf(v, pv);
        }
      }
      kappa[g] = __shfl(v, 16);
    }

    // ---- pass 2: exact streaming insert over this half, gated by min(kth, kappa) ----
    float listd = INFINITY; int listi = 0;
    #pragma unroll 2
    for (int c0 = 0; c0 < N2S/2; c0 += 64) {
      const float4 v = X[hbase + c0 + lane];
      #pragma unroll
      for (int g = 0; g < 2; g++) {
        // EXACT same distance expression as r3..r10 (keeps neighbor sets identical)
        const float d = (s1[g] + v.w) - 2.f*((qx[g]*v.x + qy[g]*v.y) + qz[g]*v.z);
        unsigned long long vote = __ballot(d < fminf(kth[g], kappa[g]));
        while (vote) {
          const int src = (int)__builtin_ctzll(vote);
          vote &= vote - 1;
          const float dv = __shfl(d, src);
          if (dv < kth[g]) {                       // uniform
            const int iv = hbase + c0 + src;
            const float ud = __shfl_up(listd, 1);
            const int   ui = __shfl_up(listi, 1);
            const bool ing = (grp == g);
            const bool cm = ing && (dv < listd);   // strict < keeps lower index on ties
            const bool cp = cm && ((lane & 15) > 0) && (dv < ud);
            listd = cm ? (cp ? ud : dv) : listd;
            listi = cm ? (cp ? ui : iv) : listi;
            kth[g] = __shfl(listd, g*16 + 15);
          }
        }
      }
    }

    // ---- exactness guard: if <16 found in this half, rescan the half unpruned ----
    {
      bool need = false;
      #pragma unroll
      for (int g = 0; g < 2; g++) need = need || (kth[g] == INFINITY);
      if (__builtin_expect(need, 0)) {
        #pragma unroll
        for (int g = 0; g < 2; g++) {
          if (kth[g] == INFINITY) {                // uniform
            if (grp == g) { listd = INFINITY; listi = 0; }
            float kk2 = INFINITY;
            for (int c0 = 0; c0 < N2S/2; c0 += 64) {
              const float4 v = X[hbase + c0 + lane];
              const float d = (s1[g] + v.w) - 2.f*((qx[g]*v.x + qy[g]*v.y) + qz[g]*v.z);
              unsigned long long vote = __ballot(d < kk2);
              while (vote) {
                const int src = (int)__builtin_ctzll(vote);
                vote &= vote - 1;
                const float dv = __shfl(d, src);
                if (dv < kk2) {
                  const int iv = hbase + c0 + src;
                  const float ud = __shfl_up(listd, 1);
                  const int   ui = __shfl_up(listi, 1);
                  const bool ing = (grp == g);
                  const bool cm = ing && (dv < listd);
                  const bool cp = cm && ((lane & 15) > 0) && (dv < ud);
                  listd = cm ? (cp ? ud : dv) : listd;
                  listi = cm ? (cp ? ui : iv) : listi;
                  kk2 = __shfl(listd, g*16 + 15);
                }
              }
            }
          }
        }
      }
    }

    // ---- store per-half partial lists ----
    if (grp < 2) {
      const int qi = (w >> 1)*2 + grp;
      pdL[qi][half][lane & 15] = listd;
      piL[qi][half][lane & 15] = listi;
    }
    __syncthreads();

    // ---- merge: wave w merges query qbase+w via 64-lane bitonic sort on (d, idx) ----
    {
      float d = (lane < 32) ? pdL[w][lane >> 4][lane & 15] : INFINITY;
      int   i = (lane < 32) ? piL[w][lane >> 4][lane & 15] : 0x7fffffff;
      #pragma unroll
      for (int k = 2; k <= 64; k <<= 1) {
        #pragma unroll
        for (int j = k >> 1; j > 0; j >>= 1) {
          const float pdv = __shfl_xor(d, j);
          const int   piv = __shfl_xor(i, j);
          const bool keepmin = (((lane & k) == 0) == ((lane & j) == 0));
          const bool ownless = (d < pdv) || (d == pdv && i < piv);
          const bool takeown = keepmin ? ownless : !ownless;
          d = takeown ? d : pdv;
          i = takeown ? i : piv;
        }
      }
      if (lane < KK) kidxL[w][lane] = i;
    }
  }
  __syncthreads();

  // ================= Phase B: gates (statement text verbatim r10; kidx from LDS) =================
  const int cq = lane & 15;                       // C col within tile (= query q)
  const int reg_o0 = w*16 + ((lane >> 4) << 2);   // first of this lane's 4 C rows
  const f32x4 zero4 = {0.f, 0.f, 0.f, 0.f};

  // ---- P0a ----
  for (int i = tid; i < 6*64; i += 256) {
    const int a = i >> 6, o = i & 63;
    const float* bp = (a==0)?b_r0:(a==1)?b_z0:(a==2)?b_h0:(a==3)?b_r1:(a==4)?b_z1:b_h1;
    biasL[a][o] = bp[o];
  }
  if (tid < 64) {
    const float* sp = points1 + ((size_t)(b*CC + tid))*N1S + n0;
    *(float4*)&p1f[tid][0] = ((const float4*)sp)[0];
  }
  ((unsigned long long*)&p1B[0][0][0])[tid] = 0ULL;   // zero 2048 B
  if (tid < 64) {                                     // dir channels (GQ*KK = 64)
    const int m = tid, qg = n0 + (m >> 4);
    const int j = kidxL[m >> 4][m & 15];
    #pragma unroll
    for (int d = 0; d < 3; d++)
      dirL[d][m] = xyz2[((size_t)(b*3+d))*N2S + j] - xyz1[((size_t)(b*3+d))*N1S + qg];
  }
  {                                                   // p2 feature gather (bf16) -> featB (B-frag packed)
    const int m = tid >> 2, qt = tid & 3;             // row m of 64, quarter qt (16 channels)
    const int ct = m >> 4;
    const int j = kidxL[ct][m & 15];
    const uint4* __restrict__ src = (const uint4*)(p2b + (((size_t)(b << 13) + j)*CC + qt*16));
    const uint4 u0 = src[0], u1 = src[1];
    *(uint4*)&featB[qt >> 1][ct][((qt & 1)*2 + 0)*16 + (m & 15)][0] = u0;
    *(uint4*)&featB[qt >> 1][ct][((qt & 1)*2 + 1)*16 + (m & 15)][0] = u1;
  }
  __syncthreads();

  // ---- P0b: p1 as B-frag (cols 0..3 valid, rest zero) ----
  {
    const int s0 = tid*4;
    const int j0 = s0 & 7, l = (s0 >> 3) & 63, kk = s0 >> 9;
    const int q = l & 15;
    if (q < GQ) {
      unsigned short t0[4];
      #pragma unroll
      for (int jj = 0; jj < 4; jj++)
        t0[jj] = f2bf(p1f[kk*32 + ((l >> 4) << 3) + j0 + jj][q]);
      uint2 pk; pk.x = t0[0] | ((unsigned)t0[1] << 16); pk.y = t0[2] | ((unsigned)t0[3] << 16);
      *(uint2*)&p1B[kk][l][j0] = pk;
    }
  }
  __syncthreads();

  // ---- P1: fuse GEMMs -> BFr/BFz ----
  {
    const bf8_t fa0 = FRAG(M_FR, 0), fa1 = FRAG(M_FR, 1);
    const bf8_t ga0 = FRAG(M_FZ, 0), ga1 = FRAG(M_FZ, 1);
    const bf8_t pb0 = *(const bf8_t*)&p1B[0][lane][0];
    const bf8_t pb1 = *(const bf8_t*)&p1B[1][lane][0];
    f32x4 ar = __builtin_amdgcn_mfma_f32_16x16x32_bf16(fa0, pb0, zero4, 0, 0, 0);
    ar = __builtin_amdgcn_mfma_f32_16x16x32_bf16(fa1, pb1, ar, 0, 0, 0);
    f32x4 az = __builtin_amdgcn_mfma_f32_16x16x32_bf16(ga0, pb0, zero4, 0, 0, 0);
    az = __builtin_amdgcn_mfma_f32_16x16x32_bf16(ga1, pb1, az, 0, 0, 0);
    if (cq < GQ) {
      #pragma unroll
      for (int r2 = 0; r2 < 4; r2++) {
        const int o = reg_o0 + r2;
        BFr[o][cq] = ar[r2] + biasL[0][o];
        BFz[o][cq] = az[r2] + biasL[1][o];
      }
    }
  }

  // ---- P1b: layer-0 r/z (+dir epilogue), write r0 B-frags, z max-reduce ----
  {
    const bf8_t ra0 = FRAG(M_R0, 0), ra1 = FRAG(M_R0, 1);
    const bf8_t za0 = FRAG(M_Z0, 0), za1 = FRAG(M_Z0, 1);
    float wdr[3][4], wdz[3][4];
    #pragma unroll
    for (int d = 0; d < 3; d++)
      #pragma unroll
      for (int r2 = 0; r2 < 4; r2++) {
        wdr[d][r2] = wdir[(0*3 + d)*64 + reg_o0 + r2];
        wdz[d][r2] = wdir[(1*3 + d)*64 + reg_o0 + r2];
      }
    const int kkv = reg_o0 >> 5, lp = ((reg_o0 & 31) >> 3)*16 + cq, j0 = reg_o0 & 7;
    #pragma unroll
    for (int ct = 0; ct < GQ; ct++) {
      const bf8_t fb0 = *(const bf8_t*)&featB[0][ct][lane][0];
      const bf8_t fb1 = *(const bf8_t*)&featB[1][ct][lane][0];
      f32x4 accr = __builtin_amdgcn_mfma_f32_16x16x32_bf16(ra0, fb0, zero4, 0, 0, 0);
      accr = __builtin_amdgcn_mfma_f32_16x16x32_bf16(ra1, fb1, accr, 0, 0, 0);
      f32x4 accz = __builtin_amdgcn_mfma_f32_16x16x32_bf16(za0, fb0, zero4, 0, 0, 0);
      accz = __builtin_amdgcn_mfma_f32_16x16x32_bf16(za1, fb1, accz, 0, 0, 0);
      const int m = ct*16 + cq;
      const float d0 = dirL[0][m], d1 = dirL[1][m], d2 = dirL[2][m];
      unsigned short rpk[4]; float zv[4];
      #pragma unroll
      for (int r2 = 0; r2 < 4; r2++) {
        const int o = reg_o0 + r2;
        float rv = accr[r2] + BFr[o][ct] + wdr[0][r2]*d0 + wdr[1][r2]*d1 + wdr[2][r2]*d2;
        rpk[r2] = f2bf(lrelu(rv));
        float zt = accz[r2] + BFz[o][ct] + wdz[0][r2]*d0 + wdz[1][r2]*d1 + wdz[2][r2]*d2;
        zv[r2] = lrelu(zt);
      }
      uint2 pk; pk.x = rpk[0] | ((unsigned)rpk[1] << 16); pk.y = rpk[2] | ((unsigned)rpk[3] << 16);
      *(uint2*)&rB[kkv][ct][lp][j0] = pk;
      #pragma unroll
      for (int r2 = 0; r2 < 4; r2++) {
        float vv = zv[r2];
        vv = fmaxf(vv, __shfl_xor(vv, 1));
        vv = fmaxf(vv, __shfl_xor(vv, 2));
        vv = fmaxf(vv, __shfl_xor(vv, 4));
        vv = fmaxf(vv, __shfl_xor(vv, 8));
        zv[r2] = vv;
      }
      if (cq == 0) {
        #pragma unroll
        for (int r2 = 0; r2 < 4; r2++) zmaxL[reg_o0 + r2][ct] = zv[r2];
      }
    }
  }
  __syncthreads();

  // ---- P2: r1 (hold r*p1 packed in regs), z1 ----
  uint2 rpK[GQ];
  float zg[4];
  {
    const bf8_t r1a0 = FRAG(M_R1, 0), r1a1 = FRAG(M_R1, 1);
    #pragma unroll
    for (int ct = 0; ct < GQ; ct++) {
      const bf8_t b0 = *(const bf8_t*)&rB[0][ct][lane][0];
      const bf8_t b1 = *(const bf8_t*)&rB[1][ct][lane][0];
      f32x4 acc = __builtin_amdgcn_mfma_f32_16x16x32_bf16(r1a0, b0, zero4, 0, 0, 0);
      acc = __builtin_amdgcn_mfma_f32_16x16x32_bf16(r1a1, b1, acc, 0, 0, 0);
      unsigned short pk4[4];
      #pragma unroll
      for (int r2 = 0; r2 < 4; r2++) {
        const int o = reg_o0 + r2;
        const float rg = sigm(acc[r2] + biasL[3][o]);
        pk4[r2] = f2bf(rg * p1f[o][ct]);
      }
      rpK[ct].x = pk4[0] | ((unsigned)pk4[1] << 16);
      rpK[ct].y = pk4[2] | ((unsigned)pk4[3] << 16);
    }
    const bf8_t z1a0 = FRAG(M_Z1, 0), z1a1 = FRAG(M_Z1, 1);
    const int qc = cq < GQ ? cq : (GQ-1);
    bf8_t zb0, zb1;
    #pragma unroll
    for (int j = 0; j < 8; j++) {
      zb0[j] = (short)f2bf(zmaxL[((lane >> 4) << 3) + j][qc]);
      zb1[j] = (short)f2bf(zmaxL[32 + ((lane >> 4) << 3) + j][qc]);
    }
    f32x4 az = __builtin_amdgcn_mfma_f32_16x16x32_bf16(z1a0, zb0, zero4, 0, 0, 0);
    az = __builtin_amdgcn_mfma_f32_16x16x32_bf16(z1a1, zb1, az, 0, 0, 0);
    #pragma unroll
    for (int r2 = 0; r2 < 4; r2++) zg[r2] = sigm(az[r2] + biasL[4][reg_o0 + r2]);
  }
  __syncthreads();

  // ---- P2b: overwrite rB with r*p1 ----
  {
    const int kkv = reg_o0 >> 5, lp = ((reg_o0 & 31) >> 3)*16 + cq, j0 = reg_o0 & 7;
    #pragma unroll
    for (int ct = 0; ct < GQ; ct++) *(uint2*)&rB[kkv][ct][lp][j0] = rpK[ct];
  }
  __syncthreads();

  // ---- P3: h0·feat + fro·(r*p1) (+dir), h max-reduce ----
  {
    const bf8_t h0a0 = FRAG(M_H0, 0), h0a1 = FRAG(M_H0, 1);
    const bf8_t foa0 = FRAG(M_FRO, 0), foa1 = FRAG(M_FRO, 1);
    float wdh[3][4];
    #pragma unroll
    for (int d = 0; d < 3; d++)
      #pragma unroll
      for (int r2 = 0; r2 < 4; r2++) wdh[d][r2] = wdir[(2*3 + d)*64 + reg_o0 + r2];
    #pragma unroll
    for (int ct = 0; ct < GQ; ct++) {
      const bf8_t fb0 = *(const bf8_t*)&featB[0][ct][lane][0];
      const bf8_t fb1 = *(const bf8_t*)&featB[1][ct][lane][0];
      const bf8_t rb0 = *(const bf8_t*)&rB[0][ct][lane][0];
      const bf8_t rb1 = *(const bf8_t*)&rB[1][ct][lane][0];
      f32x4 acc = __builtin_amdgcn_mfma_f32_16x16x32_bf16(h0a0, fb0, zero4, 0, 0, 0);
      acc = __builtin_amdgcn_mfma_f32_16x16x32_bf16(h0a1, fb1, acc, 0, 0, 0);
      acc = __builtin_amdgcn_mfma_f32_16x16x32_bf16(foa0, rb0, acc, 0, 0, 0);
      acc = __builtin_amdgcn_mfma_f32_16x16x32_bf16(foa1, rb1, acc, 0, 0, 0);
      const int m = ct*16 + cq;
      const float d0 = dirL[0][m], d1 = dirL[1][m], d2 = dirL[2][m];
      float hv[4];
      #pragma unroll
      for (int r2 = 0; r2 < 4; r2++) {
        const int o = reg_o0 + r2;
        hv[r2] = lrelu(acc[r2] + biasL[2][o] + wdh[0][r2]*d0 + wdh[1][r2]*d1 + wdh[2][r2]*d2);
      }
      #pragma unroll
      for (int r2 = 0; r2 < 4; r2++) {
        float vv = hv[r2];
        vv = fmaxf(vv, __shfl_xor(vv, 1));
        vv = fmaxf(vv, __shfl_xor(vv, 2));
        vv = fmaxf(vv, __shfl_xor(vv, 4));
        vv = fmaxf(vv, __shfl_xor(vv, 8));
        hv[r2] = vv;
      }
      if (cq == 0) {
        #pragma unroll
        for (int r2 = 0; r2 < 4; r2++) hmaxL[reg_o0 + r2][ct] = hv[r2];
      }
    }
  }
  __syncthreads();

  // ---- P4: h1, final blend ----
  {
    const bf8_t h1a0 = FRAG(M_H1, 0), h1a1 = FRAG(M_H1, 1);
    const int qc = cq < GQ ? cq : (GQ-1);
    bf8_t hb0, hb1;
    #pragma unroll
    for (int j = 0; j < 8; j++) {
      hb0[j] = (short)f2bf(hmaxL[((lane >> 4) << 3) + j][qc]);
      hb1[j] = (short)f2bf(hmaxL[32 + ((lane >> 4) << 3) + j][qc]);
    }
    f32x4 ah = __builtin_amdgcn_mfma_f32_16x16x32_bf16(h1a0, hb0, zero4, 0, 0, 0);
    ah = __builtin_amdgcn_mfma_f32_16x16x32_bf16(h1a1, hb1, ah, 0, 0, 0);
    if (cq < GQ) {
      #pragma unroll
      for (int r2 = 0; r2 < 4; r2++) {
        const int o = reg_o0 + r2;
        const float hg = tanh_(ah[r2] + biasL[5][o]);
        obuf[o][cq] = (1.f - zg[r2])*p1f[o][cq] + zg[r2]*hg;
      }
    }
  }
  __syncthreads();
  if (tid < 64)
    *(float4*)(out + ((size_t)(b*CC + tid))*N1S + n0) = *(float4*)&obuf[tid][0];
}

extern "C" void kernel_launch(void* const* d_in, const int* in_sizes, int n_in,
                              void* d_out, int out_size, void* d_ws, size_t ws_size,
                              hipStream_t stream) {
  const float* xyz1    = (const float*)d_in[0];
  const float* xyz2    = (const float*)d_in[1];
  const float* points1 = (const float*)d_in[2];
  const float* points2 = (const float*)d_in[3];
  const float* w_r0 = (const float*)d_in[4];
  const float* b_r0 = (const float*)d_in[5];
  const float* w_r1 = (const float*)d_in[6];
  const float* b_r1 = (const float*)d_in[7];
  const float* w_z0 = (const float*)d_in[8];
  const float* b_z0 = (const float*)d_in[9];
  const float* w_z1 = (const float*)d_in[10];
  const float* b_z1 = (const float*)d_in[11];
  const float* w_h0 = (const float*)d_in[12];
  const float* b_h0 = (const float*)d_in[13];
  const float* w_h1 = (const float*)d_in[14];
  const float* b_h1 = (const float*)d_in[15];
  const float* w_fr  = (const float*)d_in[16];
  const float* w_fz  = (const float*)d_in[17];
  const float* w_fro = (const float*)d_in[18];
  float* out = (float*)d_out;

  short*  wa   = (short*)d_ws;
  float*  wdir = (float*)((char*)d_ws + WDIR_OFF);
  float4* xp   = (float4*)((char*)d_ws + XP_OFF);
  unsigned short* p2b = (unsigned short*)((char*)d_ws + P2B_OFF);

  prep_misc<<<272, 256, 0, stream>>>(points2,
                                     w_r0, w_z0, w_h0, w_r1, w_z1, w_h1,
                                     w_fr, w_fz, w_fro, wa, wdir, p2b);
  pack_xyz2<<<64, 256, 0, stream>>>(xyz2, xp);

  knn_gates_kernel<<<2048, 256, 0, stream>>>(
      xyz1, xp, xyz2, points1, p2b, wa, wdir,
      b_r0, b_z0, b_h0, b_r1, b_z1, b_h1, out);
}